// Round 7
// baseline (392.612 us; speedup 1.0000x reference)
//
#include <hip/hip_runtime.h>
#include <math.h>

// DeltaBlock forward, MI355X. All proxy layers / attention distances are L1-cdists
// (stop_gradient(l1-l2)+l2 == l1 forward). R7: u8 v_sad_u8 cdists (exact).
// R8: attention PV via mfma_f32_16x16x32_f16. R9/R10: occupancy + fusion.
// R11: transcendental diet. R12: step-10 atomics removed (u16 split-K partials).
// R13: occupancy collapse. R14/R15/R16/R17 (neutral-ish): X-in-regs, 2x
// occupancy, barrier-free staging — none moved the ~65% VALUBusy cap.
// Conclusion: the LDS pipe (1/CU, shared by 32 waves) is co-bottleneck by
// INSTRUCTION COUNT (24 reads + ~10 writes per k0 per wave).
// R18: ZERO-LDS cdist — both operands read straight from global per 16B
// k-half; L1 dedups the cross-lane duplication (X 16 lanes/addr, W 4/addr).
// No ds instrs, no barriers, no staging. Two-half k0 keeps VGPR <= ~70.

#define NROWS  2048
#define DMODEL 512
#define TSEQ   1024
#define HIDDEN 2048

typedef _Float16 hf;
typedef hf h2 __attribute__((ext_vector_type(2)));
typedef hf h4 __attribute__((ext_vector_type(4)));
typedef hf h8 __attribute__((ext_vector_type(8)));
typedef float f32x4 __attribute__((ext_vector_type(4)));

#if defined(__has_builtin)
#if __has_builtin(__builtin_amdgcn_sad_u8)
#define HAVE_SAD 1
#endif
#if __has_builtin(__builtin_amdgcn_mfma_f32_16x16x32_f16)
#define HAVE_MFMA 1
#endif
#endif

__device__ __forceinline__ unsigned sad8(unsigned a, unsigned b, unsigned c) {
#ifdef HAVE_SAD
  return __builtin_amdgcn_sad_u8(a, b, c);
#else
  unsigned r;
  asm("v_sad_u8 %0, %1, %2, %3" : "=v"(r) : "v"(a), "v"(b), "v"(c));
  return r;
#endif
}

// fast tanh: sign(x)*(1-t)/(1+t), t=e^(-2|x|); err ~1e-7 << q8 step 4e-3
__device__ __forceinline__ float ftanh(float x) {
  const float t = __expf(-2.0f * fabsf(x));
  const float r = (1.0f - t) / (1.0f + t);
  return copysignf(r, x);
}

// x^p for x>=1 (no edge cases): exp2(p*log2(x)) via raw v_log/v_exp
__device__ __forceinline__ float fpow_ge1(float x, float p) {
  float lg, r;
  asm("v_log_f32 %0, %1" : "=v"(lg) : "v"(x));
  const float e = lg * p;
  asm("v_exp_f32 %0, %1" : "=v"(r) : "v"(e));
  return r;
}

__device__ __forceinline__ unsigned q8(float x) {   // tanh-range (-1,1) -> u8
  return (unsigned)(int)((x + 1.0f) * 127.5f + 0.5f);
}

struct CP { const float* g0; const float* g1; const float* g2; };

// ---------------- LayerNorm: f32 row -> (optional f32 out) + tanh-u8 out ---
// zf: optional zero-fill target (accO+accR), 130 float4 per block (exact).
__global__ __launch_bounds__(256) void ln_kernel(
    const float* __restrict__ X, const float* __restrict__ w,
    const float* __restrict__ bb, float* __restrict__ outPlain,
    unsigned char* __restrict__ out8, float4* __restrict__ zf)
{
  const int n = blockIdx.x, tid = threadIdx.x;
  if (zf && tid < 130)
    zf[(size_t)n * 130 + tid] = make_float4(0.f, 0.f, 0.f, 0.f);
  const float* row = X + (size_t)n * DMODEL;
  float2 v = *(const float2*)&row[tid * 2];
  float s1 = v.x + v.y;
  float s2 = v.x * v.x + v.y * v.y;
#pragma unroll
  for (int off = 1; off < 64; off <<= 1) {
    s1 += __shfl_xor(s1, off);
    s2 += __shfl_xor(s2, off);
  }
  __shared__ float red[8];
  if ((tid & 63) == 0) { red[(tid >> 6) * 2] = s1; red[(tid >> 6) * 2 + 1] = s2; }
  __syncthreads();
  s1 = red[0] + red[2] + red[4] + red[6];
  s2 = red[1] + red[3] + red[5] + red[7];
  const float mu   = s1 * (1.0f / DMODEL);
  const float var  = s2 * (1.0f / DMODEL) - mu * mu;
  const float rstd = rsqrtf(var + 1e-5f);
  const int d = tid * 2;
  const float y0 = (v.x - mu) * rstd * w[d]     + bb[d];
  const float y1 = (v.y - mu) * rstd * w[d + 1] + bb[d + 1];
  if (outPlain) *(float2*)&outPlain[(size_t)n * DMODEL + d] = make_float2(y0, y1);
  const unsigned a = q8(ftanh(y0)), b = q8(ftanh(y1));
  *(unsigned short*)&out8[(size_t)n * DMODEL + d] = (unsigned short)(a | (b << 8));
}

// ---------------- tanh + quantize u8, up to 3 sources (z-indexed) ----------
__global__ __launch_bounds__(256) void tanhcvt8m_kernel(
    const float* __restrict__ s0, const float* __restrict__ s1,
    const float* __restrict__ s2, unsigned char* __restrict__ out, int K)
{
  const int z = blockIdx.y;
  const float* sb = (z == 0) ? s0 : (z == 1) ? s1 : s2;
  const int rows = (int)gridDim.x * 2;
  const int row = blockIdx.x * 2 + (threadIdx.x >> 7);
  const int t = threadIdx.x & 127;
  const float* src = sb + (size_t)row * K;
  unsigned char* dst = out + ((size_t)z * rows + row) * K;
  for (int k = t * 4; k < K; k += 512) {
    float4 v = *(const float4*)&src[k];
    unsigned pk = q8(ftanh(v.x)) | (q8(ftanh(v.y)) << 8) |
                  (q8(ftanh(v.z)) << 16) | (q8(ftanh(v.w)) << 24);
    *(unsigned*)&dst[k] = pk;
  }
}

// ---------------- u8 SAD cdist kernel, ZERO-LDS ----------------------------
// block tile 64 rows x 32 cols, 256 threads (4 waves). Thread (tx,ty) owns
// rows n0+ty*4..+3 and cols m0+tx*2..+1 (x NCD). Per 16B k-half: 4 X uint4
// (4 unique addrs, L1 broadcast) + NCD*2 W uint4 (16 unique addrs) ->
// NCD*32 sads. No LDS, no barriers, no staging.
// EPI 1: QKV, blockIdx.z = {0:q, 1:k, 2:v}; q,k -> tanh u8, v -> f16 transposed.
// EPI 2: gate/val (NCD=2) -> tanh(silu(g)*v) u8.
// EPI 3: split-K partial (blockIdx.z = K-slice) -> u16 plain stores into
//        contiguous pf (slice stride NROWS*M u16); (acc+1)>>1 fits u16 at
//        Kc=512 (max 130560/2); rounding err <= 2 counts total.
template <int NCD, int EPI>
__global__ __launch_bounds__(256, 6) void cdistz_kernel(
    const unsigned char* __restrict__ X8, const unsigned char* __restrict__ W8,
    CP cp,
    unsigned char* __restrict__ o8a, unsigned char* __restrict__ o8b,
    hf* __restrict__ vt16, unsigned char* __restrict__ gvt8,
    unsigned short* __restrict__ pf,
    int M, int K, int Kc, float invK127)
{
  const int m0 = blockIdx.x * 32, n0 = blockIdx.y * 64;
  const int zc = (EPI == 1) ? blockIdx.z : 0;          // QKV: z picks cdist
  const int kb = (EPI == 3) ? blockIdx.z * Kc : 0;     // split-K slice
  const int tid = threadIdx.x, tx = tid & 15, ty = tid >> 4;
  unsigned acc[NCD][4][2] = {};

  const unsigned char* xb = X8 + (size_t)(n0 + ty * 4) * K + kb;
  const unsigned char* wb = W8 + (size_t)zc * M * K + (size_t)(m0 + tx * 2) * K + kb;

#pragma unroll 1
  for (int k0 = 0; k0 < Kc; k0 += 32) {
#pragma unroll
    for (int half = 0; half < 2; half++) {
      const int ko = k0 + half * 16;
      uint4 xv0 = *(const uint4*)(xb + ko);
      uint4 xv1 = *(const uint4*)(xb + (size_t)K + ko);
      uint4 xv2 = *(const uint4*)(xb + (size_t)2 * K + ko);
      uint4 xv3 = *(const uint4*)(xb + (size_t)3 * K + ko);
      uint4 wv[NCD][2];
#pragma unroll
      for (int c = 0; c < NCD; c++) {
        wv[c][0] = *(const uint4*)(wb + (size_t)c * M * K + ko);
        wv[c][1] = *(const uint4*)(wb + (size_t)c * M * K + (size_t)K + ko);
      }
      const unsigned xd[4][4] = {
        {xv0.x, xv0.y, xv0.z, xv0.w},
        {xv1.x, xv1.y, xv1.z, xv1.w},
        {xv2.x, xv2.y, xv2.z, xv2.w},
        {xv3.x, xv3.y, xv3.z, xv3.w}};
#pragma unroll
      for (int kk = 0; kk < 4; kk++) {
#pragma unroll
        for (int c = 0; c < NCD; c++) {
          const unsigned w0 = (kk == 0) ? wv[c][0].x : (kk == 1) ? wv[c][0].y
                            : (kk == 2) ? wv[c][0].z : wv[c][0].w;
          const unsigned w1 = (kk == 0) ? wv[c][1].x : (kk == 1) ? wv[c][1].y
                            : (kk == 2) ? wv[c][1].z : wv[c][1].w;
#pragma unroll
          for (int i = 0; i < 4; i++) {
            acc[c][i][0] = sad8(xd[i][kk], w0, acc[c][i][0]);
            acc[c][i][1] = sad8(xd[i][kk], w1, acc[c][i][1]);
          }
        }
      }
    }
  }

  if constexpr (EPI == 1) {                  // QKV, z-selected cdist (NCD=1)
    if (zc < 2) {                            // q or k -> tanh u8
      unsigned char* o8 = zc ? o8b : o8a;
      const float* gn = zc ? cp.g1 : cp.g0;
#pragma unroll
      for (int i = 0; i < 4; i++) {
        const int n = n0 + ty * 4 + i;
        unsigned pk = 0;
#pragma unroll
        for (int j = 0; j < 2; j++) {
          const int m = m0 + tx * 2 + j;
          const float val = (0.5f - (float)acc[0][i][j] * invK127) * gn[m];
          pk |= q8(ftanh(val)) << (8 * j);
        }
        *(unsigned short*)&o8[(size_t)n * M + m0 + tx * 2] = (unsigned short)pk;
      }
    } else {                                 // v -> f16 transposed [bh][d][t]
#pragma unroll
      for (int i = 0; i < 4; i++) {
        const int n = n0 + ty * 4 + i;
        const int b = n >> 10, t = n & 1023;
#pragma unroll
        for (int j = 0; j < 2; j++) {
          const int m = m0 + tx * 2 + j;
          const float vv = (0.5f - (float)acc[0][i][j] * invK127) * cp.g2[m];
          vt16[((size_t)(b * 8 + (m >> 6)) * 64 + (m & 63)) * 1024 + t] = (hf)vv;
        }
      }
    }
  } else if constexpr (EPI == 2) {           // gate/val: NCD=2
#pragma unroll
    for (int i = 0; i < 4; i++) {
      const int n = n0 + ty * 4 + i;
      unsigned pk = 0;
#pragma unroll
      for (int j = 0; j < 2; j++) {
        const int m = m0 + tx * 2 + j;
        float g = (0.5f - (float)acc[0][i][j] * invK127) * cp.g0[m];
        g = g / (1.0f + __expf(-g));         // silu
        const float vv = (0.5f - (float)acc[1][i][j] * invK127) * cp.g1[m];
        pk |= q8(ftanh(g * vv)) << (8 * j);
      }
      *(unsigned short*)&gvt8[(size_t)n * M + m0 + tx * 2] = (unsigned short)pk;
    }
  } else {                                   // EPI==3: u16 partials, plain stores
    unsigned short* pz = pf + (size_t)blockIdx.z * ((size_t)NROWS * M);
#pragma unroll
    for (int i = 0; i < 4; i++) {
      const int n = n0 + ty * 4 + i;
      const unsigned p0 = (acc[0][i][0] + 1) >> 1;
      const unsigned p1 = (acc[0][i][1] + 1) >> 1;
      *(unsigned*)&pz[(size_t)n * M + m0 + tx * 2] = p0 | (p1 << 16);
    }
  }
}

// ---------------- attention: split-S partial (u8 SAD QK, MFMA PV) ----------
// grid (144, 16): chunk = (tt, <=2 s-tiles). Per bh: sum ceil((tt/2+1)/2) = 144.
__global__ __launch_bounds__(256) void attn_part_kernel(
    const unsigned char* __restrict__ Qb, const unsigned char* __restrict__ Kb,
    const hf* __restrict__ Vt,
    const float* __restrict__ gamma, const float* __restrict__ rho,
    float* __restrict__ accO, float* __restrict__ accR)
{
  const int bh = blockIdx.y, b = bh >> 3, h = bh & 7;
  int rem = 143 - (int)blockIdx.x;              // heavy (high-tt) chunks first
  int tt = 0;
  for (;;) {
    const int nc = ((tt >> 1) + 2) >> 1;        // ceil((tt/2+1)/2)
    if (rem < nc) break;
    rem -= nc; ++tt;
  }
  const int ntile = (tt >> 1) + 1;
  const int sb = rem * 2;
  const int se = (sb + 2 < ntile) ? sb + 2 : ntile;
  const int t0 = tt * 32;

  const float gp = log1pf(expf(gamma[h]));
  const float nrp = -log1pf(expf(rho[h]));      // -rho softplus (pow exponent)
  const size_t base8 = ((size_t)b * TSEQ) * DMODEL + h * 64;

  __shared__ unsigned qs8[16][36];   // [kk4][t]
  __shared__ unsigned ks8[16][68];   // [kk4][s]
  __shared__ hf awt[32][72];         // AW [t][s] row-major (+pad)
  __shared__ hf vsm[64][72];         // V  [d][s] row-major (+pad)

  const int tid = threadIdx.x, tx = tid & 15, ty = tid >> 4;
  const int tx4 = tx * 4, ty2 = ty * 2;
  const int lane = tid & 63, wv = tid >> 6;
  const float SCALE_D = 1.0f / (127.5f * 8.0f);   // sad -> l1/Dh*sqrt(Dh)

  {  // Q tile 32x64 u8, transposed into dword-rows
    const int r = tid >> 3, p = (tid & 7) * 2;
    uint2 a = *(const uint2*)&Qb[base8 + (size_t)(t0 + r) * DMODEL + (tid & 7) * 8];
    qs8[p + 0][r] = a.x;
    qs8[p + 1][r] = a.y;
  }

  float rsum[2] = {};
  f32x4 cacc[2] = {};                // MFMA accumulators: [mtile] x 4 f32

  const int vd = tid >> 2, vs16 = (tid & 3) * 16;
  const int arow = lane & 15;        // MFMA m/n index
  const int koff = (lane >> 4) * 8;  // MFMA k sub-offset

  for (int st = sb; st < se; ++st) {
    const int s0 = st * 64;
    __syncthreads();
    {  // K tile 64x64 u8 (transposed dwords)
      const int r = tid >> 2, p = (tid & 3) * 4;
      uint4 a = *(const uint4*)&Kb[base8 + (size_t)(s0 + r) * DMODEL + (tid & 3) * 16];
      ks8[p + 0][r] = a.x;
      ks8[p + 1][r] = a.y;
      ks8[p + 2][r] = a.z;
      ks8[p + 3][r] = a.w;
      // V tile: transposed f16 in HBM -> plain [d][s] rows in LDS
      const hf* vsrc = &Vt[((size_t)bh * 64 + vd) * 1024 + s0 + vs16];
      *(h8*)&vsm[vd][vs16 + 0] = *(const h8*)vsrc;
      *(h8*)&vsm[vd][vs16 + 8] = *(const h8*)(vsrc + 8);
    }
    __syncthreads();

    // L1 via v_sad_u8 (exact integer)
    unsigned sacc[2][4] = {};
#pragma unroll
    for (int kk = 0; kk < 16; kk++) {
      uint2 qa = *(const uint2*)&qs8[kk][ty2];
      uint4 kb4 = *(const uint4*)&ks8[kk][tx4];
      const unsigned kk4[4] = {kb4.x, kb4.y, kb4.z, kb4.w};
#pragma unroll
      for (int j = 0; j < 4; j++) {
        sacc[0][j] = sad8(qa.x, kk4[j], sacc[0][j]);
        sacc[1][j] = sad8(qa.y, kk4[j], sacc[1][j]);
      }
    }

    // kernel weights + causal mask -> f16 [t][s] in LDS
#pragma unroll
    for (int i = 0; i < 2; i++) {
      const int tg = t0 + ty2 + i;
      h4 pk;
#pragma unroll
      for (int j = 0; j < 4; j++) {
        const int sg = s0 + tx4 + j;
        const float dist = (float)sacc[i][j] * SCALE_D;
        const float bsx = fmaf(gp, dist * dist, 1.0f + 1e-6f);
        float aw = fpow_ge1(bsx, nrp);              // bsx>=1: raw log/exp
        aw = (sg <= tg) ? aw : 0.0f;
        pk[j] = (hf)aw;
        rsum[i] += aw;
      }
      *(h4*)&awt[ty2 + i][tx4] = pk;
    }
    __syncthreads();

    // PV: O[32x64] += AW[32x64] @ V[64x64] via MFMA (wave wv owns d-cols 16wv..)
#ifdef HAVE_MFMA
#pragma unroll
    for (int ks = 0; ks < 2; ks++) {
      h8 bfrag = *(const h8*)&vsm[wv * 16 + arow][ks * 32 + koff];
      h8 afr0  = *(const h8*)&awt[arow]          [ks * 32 + koff];
      h8 afr1  = *(const h8*)&awt[16 + arow]     [ks * 32 + koff];
      cacc[0] = __builtin_amdgcn_mfma_f32_16x16x32_f16(afr0, bfrag, cacc[0], 0, 0, 0);
      cacc[1] = __builtin_amdgcn_mfma_f32_16x16x32_f16(afr1, bfrag, cacc[1], 0, 0, 0);
    }
#else
    {
      const int crow = (lane >> 4) * 4;
      const int d = wv * 16 + (lane & 15);
#pragma unroll
      for (int mt = 0; mt < 2; mt++)
#pragma unroll
        for (int r = 0; r < 4; r++) {
          const int t = mt * 16 + crow + r;
          float s = cacc[mt][r];
          for (int si = 0; si < 64; si++)
            s += (float)awt[t][si] * (float)vsm[d][si];
          cacc[mt][r] = s;
        }
    }
#endif
  }

#pragma unroll
  for (int off = 1; off < 16; off <<= 1) {
    rsum[0] += __shfl_xor(rsum[0], off);
    rsum[1] += __shfl_xor(rsum[1], off);
  }
  float* aO = accO + ((size_t)bh * TSEQ + t0) * 64;
  {   // C/D layout: col=lane&15 (d), row=(lane>>4)*4+reg (t)
    const int crow = (lane >> 4) * 4;
    const int ccol = wv * 16 + (lane & 15);
#pragma unroll
    for (int mt = 0; mt < 2; mt++)
#pragma unroll
      for (int r = 0; r < 4; r++)
        atomicAdd(&aO[(size_t)(mt * 16 + crow + r) * 64 + ccol], cacc[mt][r]);
  }
#pragma unroll
  for (int i = 0; i < 2; i++)
    if (tx == 0) atomicAdd(&accR[bh * TSEQ + t0 + ty2 + i], rsum[i]);
}

// ---------------- wo GEMM + residual, attn-normalize fused in staging ------
// Xn = accO [bh][1024][64]; logical attn[n][c] = Xn[bh(n,c)][t(n)][c&63]/rsum.
__global__ __launch_bounds__(256) void gemm_res_kernel(
    const float* __restrict__ Xn, const float* __restrict__ accR,
    const float* __restrict__ W,
    const float* __restrict__ bias, const float* __restrict__ Res,
    float* __restrict__ Out)
{
  const int m0 = blockIdx.x * 64, n0 = blockIdx.y * 64;
  __shared__ float xs[16][68];
  __shared__ float wsm[16][68];
  const int tid = threadIdx.x, tx = tid & 15, ty = tid >> 4;
  const int lr = tid >> 2, lc4 = (tid & 3) * 4;
  float acc[4][4] = {};
  const int n = n0 + lr;
  const float* wp = &W[(size_t)(m0 + lr) * DMODEL + lc4];
  for (int k0 = 0; k0 < DMODEL; k0 += 16) {
    const int c = k0 + lc4;
    const size_t arow = ((size_t)((n >> 10) * 8 + (c >> 6))) * TSEQ + (n & 1023);
    float4 xv = *(const float4*)&Xn[arow * 64 + (c & 63)];
    const float inv = 1.0f / (accR[arow] + 1e-6f);
    xv.x *= inv; xv.y *= inv; xv.z *= inv; xv.w *= inv;
    float4 wv = *(const float4*)(wp + k0);
    __syncthreads();
    xs [lc4 + 0][lr] = xv.x; xs [lc4 + 1][lr] = xv.y; xs [lc4 + 2][lr] = xv.z; xs [lc4 + 3][lr] = xv.w;
    wsm[lc4 + 0][lr] = wv.x; wsm[lc4 + 1][lr] = wv.y; wsm[lc4 + 2][lr] = wv.z; wsm[lc4 + 3][lr] = wv.w;
    __syncthreads();
#pragma unroll
    for (int kk = 0; kk < 16; kk++) {
      float4 av = *(const float4*)&xs[kk][ty * 4];
      float4 bv = *(const float4*)&wsm[kk][tx * 4];
      const float aa[4] = {av.x, av.y, av.z, av.w};
      const float bs[4] = {bv.x, bv.y, bv.z, bv.w};
#pragma unroll
      for (int i = 0; i < 4; i++)
#pragma unroll
        for (int j = 0; j < 4; j++) acc[i][j] = fmaf(aa[i], bs[j], acc[i][j]);
    }
  }
#pragma unroll
  for (int i = 0; i < 4; i++) {
    const int nn = n0 + ty * 4 + i;
    float o[4];
#pragma unroll
    for (int j = 0; j < 4; j++) {
      const int m = m0 + tx * 4 + j;
      o[j] = acc[i][j] + bias[m] + Res[(size_t)nn * DMODEL + m];
    }
    *(float4*)&Out[(size_t)nn * DMODEL + m0 + tx * 4] = make_float4(o[0], o[1], o[2], o[3]);
  }
}

// ---------------- final combine (fused out-proxy epilogue) ------------------
// out = x2 + f + 0.5*|shift(h) - sigmoid(dir_w)|, f from u16 split-K partials
// (each partial = round(acc_z/2); sum of 4 slices, scale 2x folded into invf).
__global__ void final_kernel(const float* __restrict__ x2,
                             const unsigned short* __restrict__ pf,
                             const float* __restrict__ outg,
                             const float* __restrict__ h,
                             const float* __restrict__ dirw,
                             float* __restrict__ out)
{
  const int i4 = blockIdx.x * 256 + threadIdx.x;
  const int n = i4 >> 7;
  const int t = n & (TSEQ - 1);
  const int d4 = (i4 & 127) * 4;
  float4 xv = *(const float4*)&x2[(size_t)i4 * 4];
  const size_t off = (size_t)i4 * 4;
  unsigned s[4] = {};
#pragma unroll
  for (int z = 0; z < 4; z++) {
    uint2 a = *(const uint2*)&pf[(size_t)z * ((size_t)NROWS * DMODEL) + off];
    s[0] += (a.x & 0xffffu);
    s[1] += (a.x >> 16);
    s[2] += (a.y & 0xffffu);
    s[3] += (a.y >> 16);
  }
  float4 hv = make_float4(0.f, 0.f, 0.f, 0.f);
  if (t != 0) hv = *(const float4*)&h[(size_t)(i4 - 128) * 4];
  const float xx[4] = {xv.x, xv.y, xv.z, xv.w};
  const float hh[4] = {hv.x, hv.y, hv.z, hv.w};
  const float invf = 2.0f / (127.5f * 2048.0f);   // 2x: partials store acc/2
  float o[4];
#pragma unroll
  for (int j = 0; j < 4; j++) {
    const float f = (0.5f - (float)s[j] * invf) * outg[d4 + j];
    const float sg = 1.0f / (1.0f + __expf(-dirw[d4 + j]));
    o[j] = xx[j] + f + 0.5f * fabsf(hh[j] - sg);
  }
  *(float4*)&out[(size_t)i4 * 4] = make_float4(o[0], o[1], o[2], o[3]);
}

// ---------------------------------------------------------------------------
extern "C" void kernel_launch(void* const* d_in, const int* in_sizes, int n_in,
                              void* d_out, int out_size, void* d_ws, size_t ws_size,
                              hipStream_t stream)
{
  (void)in_sizes; (void)n_in; (void)out_size;
  const float* x      = (const float*)d_in[0];
  const float* ln1_w  = (const float*)d_in[1];
  const float* ln1_b  = (const float*)d_in[2];
  const float* wq_w   = (const float*)d_in[3];
  const float* wq_g   = (const float*)d_in[4];
  const float* wk_w   = (const float*)d_in[5];
  const float* wk_g   = (const float*)d_in[6];
  const float* wv_w   = (const float*)d_in[7];
  const float* wv_g   = (const float*)d_in[8];
  const float* wo_w   = (const float*)d_in[9];
  const float* wo_b   = (const float*)d_in[10];
  const float* gamma  = (const float*)d_in[11];
  const float* rho    = (const float*)d_in[12];
  const float* ln2_w  = (const float*)d_in[13];
  const float* ln2_b  = (const float*)d_in[14];
  const float* gate_w = (const float*)d_in[15];
  const float* gate_g = (const float*)d_in[16];
  const float* val_w  = (const float*)d_in[17];
  const float* val_g  = (const float*)d_in[18];
  const float* out_w  = (const float*)d_in[19];
  const float* out_g  = (const float*)d_in[20];
  const float* dir_w  = (const float*)d_in[21];
  float* out = (float*)d_out;

  if (ws_size < ((size_t)32 << 20)) return;
  unsigned char* wsb = (unsigned char*)d_ws;

  unsigned char* w8   = wsb;                          // [0,2MB) weights u8
  unsigned char* x8   = wsb + ((size_t)2 << 20);      // xt8; later ht8
  unsigned char* q8b  = wsb + ((size_t)3 << 20);
  unsigned char* k8b  = wsb + ((size_t)4 << 20);
  hf*            vt16 = (hf*)(wsb + ((size_t)5 << 20));       // 2MB
  unsigned char* gvt8 = wsb + ((size_t)7 << 20);              // 4MB
  float*         accO = (float*)(wsb + ((size_t)11 << 20));   // 4MB
  float*         accR = (float*)(wsb + ((size_t)15 << 20));   // 64KB (contig w/ accO)
  unsigned short* pf  = (unsigned short*)(wsb + ((size_t)16 << 20)); // 8MB, 4 u16 slices
  float*         x2   = (float*)(wsb + ((size_t)24 << 20));   // 4MB
  float*         hbuf = (float*)(wsb + ((size_t)28 << 20));   // 4MB

  // 1. xt8 = q8(tanh(LN1(x))); also zeroes accO+accR (130 float4/block)
  ln_kernel<<<NROWS, 256, 0, stream>>>(x, ln1_w, ln1_b, nullptr, x8,
                                       (float4*)accO);

  // 2. q/k/v weights -> tanh u8 (one fused dispatch, z-indexed)
  tanhcvt8m_kernel<<<dim3(256, 3), 256, 0, stream>>>(wq_w, wk_w, wv_w, w8, 512);

  // 3. q,k,v cdists (SAD), z-split; q/k -> u8, v -> f16 transposed
  {
    CP cp; cp.g0 = wq_g; cp.g1 = wk_g; cp.g2 = wv_g;
    cdistz_kernel<1, 1><<<dim3(16, 32, 3), 256, 0, stream>>>(
        x8, w8, cp, q8b, k8b, vt16, nullptr, nullptr,
        512, 512, 512, 1.0f / (127.5f * 512.0f));
  }

  // 4. attention: split-S partial (accO/accR pre-zeroed by step 1)
  attn_part_kernel<<<dim3(144, 16), 256, 0, stream>>>(q8b, k8b, vt16,
                                                      gamma, rho, accO, accR);

  // 5. x2 = x + normalize(accO/accR) @ wo^T + wo_b  (normalize fused)
  gemm_res_kernel<<<dim3(8, 32), 256, 0, stream>>>(accO, accR, wo_w, wo_b, x, x2);

  // 6. h (f32) + ht8 = LN2(x2)
  ln_kernel<<<NROWS, 256, 0, stream>>>(x2, ln2_w, ln2_b, hbuf, x8, nullptr);

  // 7. gate/val weights -> tanh u8 (one fused dispatch)
  tanhcvt8m_kernel<<<dim3(1024, 2), 256, 0, stream>>>(gate_w, val_w, val_w, w8, 512);

  // 8. gvt8 = q8(tanh(silu(gate)*val)), zero-LDS: 2048 blocks
  {
    CP cp; cp.g0 = gate_g; cp.g1 = val_g; cp.g2 = nullptr;
    cdistz_kernel<2, 2><<<dim3(64, 32, 1), 256, 0, stream>>>(
        x8, w8, cp, nullptr, nullptr, nullptr, gvt8, nullptr,
        2048, 512, 512, 1.0f / (127.5f * 512.0f));
  }

  // 9. out_w -> tanh u8 (512 rows, K=2048)
  tanhcvt8m_kernel<<<dim3(256, 1), 256, 0, stream>>>(out_w, out_w, out_w, w8, 2048);

  // 10. out-proxy partial sums (K=2048): zero-LDS, split-K=4, u16 plain
  //     stores (no memset, no atomics). 2048 blocks.
  {
    CP cp; cp.g0 = out_g; cp.g1 = nullptr; cp.g2 = nullptr;
    cdistz_kernel<1, 3><<<dim3(16, 32, 4), 256, 0, stream>>>(
        gvt8, w8, cp, nullptr, nullptr, nullptr, nullptr, pf,
        512, 2048, 512, 0.0f);
  }

  // 11. out = x2 + f(partials) + 0.5*|shift(h) - sigmoid(dir_w)|  (fepi fused)
  final_kernel<<<1024, 256, 0, stream>>>(x2, pf, out_g, hbuf, dir_w, out);
}

// Round 8
// 160.114 us; speedup vs baseline: 2.4521x; 2.4521x over previous
//
#include <hip/hip_runtime.h>
#include <math.h>

// DeltaBlock forward, MI355X. All proxy layers / attention distances are L1-cdists
// (stop_gradient(l1-l2)+l2 == l1 forward). R7: u8 v_sad_u8 cdists (exact).
// R8: attention PV via mfma_f32_16x16x32_f16. R9/R10: occupancy + fusion.
// R11: transcendental diet. R12: step-10 atomics removed (u16 split-K partials).
// R13: occupancy collapse. R14-R17: operand-placement sweep -> LDS pipe is
// co-bottleneck by INSTRUCTION COUNT (~30 ds-instrs vs 128 sads per k0/wave).
// R18 (FAILED 3.3x): zero-LDS — TA/L1 does NOT dedup broadcast lanes; vmem-
// issue-bound at 20% VALU. LDS broadcast is the right delivery path.
// R19: R16 structure + kk-PAIRED W layout — W stored [kkp][col*2+half]:
// one ds_write_b64 stages 2 kks; one b128 read serves 2 kks x 2 cols.
// Inner reads/k0: 24 -> 16 (NCD=2), 16 -> 12 (NCD=1). One barrier per k0.
// Keeps R17's ln-fused accO/accR zeroing (no memset dispatch).

#define NROWS  2048
#define DMODEL 512
#define TSEQ   1024
#define HIDDEN 2048

typedef _Float16 hf;
typedef hf h2 __attribute__((ext_vector_type(2)));
typedef hf h4 __attribute__((ext_vector_type(4)));
typedef hf h8 __attribute__((ext_vector_type(8)));
typedef float f32x4 __attribute__((ext_vector_type(4)));

#if defined(__has_builtin)
#if __has_builtin(__builtin_amdgcn_sad_u8)
#define HAVE_SAD 1
#endif
#if __has_builtin(__builtin_amdgcn_mfma_f32_16x16x32_f16)
#define HAVE_MFMA 1
#endif
#endif

__device__ __forceinline__ unsigned sad8(unsigned a, unsigned b, unsigned c) {
#ifdef HAVE_SAD
  return __builtin_amdgcn_sad_u8(a, b, c);
#else
  unsigned r;
  asm("v_sad_u8 %0, %1, %2, %3" : "=v"(r) : "v"(a), "v"(b), "v"(c));
  return r;
#endif
}

// fast tanh: sign(x)*(1-t)/(1+t), t=e^(-2|x|); err ~1e-7 << q8 step 4e-3
__device__ __forceinline__ float ftanh(float x) {
  const float t = __expf(-2.0f * fabsf(x));
  const float r = (1.0f - t) / (1.0f + t);
  return copysignf(r, x);
}

// x^p for x>=1 (no edge cases): exp2(p*log2(x)) via raw v_log/v_exp
__device__ __forceinline__ float fpow_ge1(float x, float p) {
  float lg, r;
  asm("v_log_f32 %0, %1" : "=v"(lg) : "v"(x));
  const float e = lg * p;
  asm("v_exp_f32 %0, %1" : "=v"(r) : "v"(e));
  return r;
}

__device__ __forceinline__ unsigned q8(float x) {   // tanh-range (-1,1) -> u8
  return (unsigned)(int)((x + 1.0f) * 127.5f + 0.5f);
}

struct CP { const float* g0; const float* g1; const float* g2; };

// ---------------- LayerNorm: f32 row -> (optional f32 out) + tanh-u8 out ---
// zf: optional zero-fill target (accO+accR), 130 float4 per block (exact).
__global__ __launch_bounds__(256) void ln_kernel(
    const float* __restrict__ X, const float* __restrict__ w,
    const float* __restrict__ bb, float* __restrict__ outPlain,
    unsigned char* __restrict__ out8, float4* __restrict__ zf)
{
  const int n = blockIdx.x, tid = threadIdx.x;
  if (zf && tid < 130)
    zf[(size_t)n * 130 + tid] = make_float4(0.f, 0.f, 0.f, 0.f);
  const float* row = X + (size_t)n * DMODEL;
  float2 v = *(const float2*)&row[tid * 2];
  float s1 = v.x + v.y;
  float s2 = v.x * v.x + v.y * v.y;
#pragma unroll
  for (int off = 1; off < 64; off <<= 1) {
    s1 += __shfl_xor(s1, off);
    s2 += __shfl_xor(s2, off);
  }
  __shared__ float red[8];
  if ((tid & 63) == 0) { red[(tid >> 6) * 2] = s1; red[(tid >> 6) * 2 + 1] = s2; }
  __syncthreads();
  s1 = red[0] + red[2] + red[4] + red[6];
  s2 = red[1] + red[3] + red[5] + red[7];
  const float mu   = s1 * (1.0f / DMODEL);
  const float var  = s2 * (1.0f / DMODEL) - mu * mu;
  const float rstd = rsqrtf(var + 1e-5f);
  const int d = tid * 2;
  const float y0 = (v.x - mu) * rstd * w[d]     + bb[d];
  const float y1 = (v.y - mu) * rstd * w[d + 1] + bb[d + 1];
  if (outPlain) *(float2*)&outPlain[(size_t)n * DMODEL + d] = make_float2(y0, y1);
  const unsigned a = q8(ftanh(y0)), b = q8(ftanh(y1));
  *(unsigned short*)&out8[(size_t)n * DMODEL + d] = (unsigned short)(a | (b << 8));
}

// ---------------- tanh + quantize u8, up to 3 sources (z-indexed) ----------
__global__ __launch_bounds__(256) void tanhcvt8m_kernel(
    const float* __restrict__ s0, const float* __restrict__ s1,
    const float* __restrict__ s2, unsigned char* __restrict__ out, int K)
{
  const int z = blockIdx.y;
  const float* sb = (z == 0) ? s0 : (z == 1) ? s1 : s2;
  const int rows = (int)gridDim.x * 2;
  const int row = blockIdx.x * 2 + (threadIdx.x >> 7);
  const int t = threadIdx.x & 127;
  const float* src = sb + (size_t)row * K;
  unsigned char* dst = out + ((size_t)z * rows + row) * K;
  for (int k = t * 4; k < K; k += 512) {
    float4 v = *(const float4*)&src[k];
    unsigned pk = q8(ftanh(v.x)) | (q8(ftanh(v.y)) << 8) |
                  (q8(ftanh(v.z)) << 16) | (q8(ftanh(v.w)) << 24);
    *(unsigned*)&dst[k] = pk;
  }
}

// ---------------- u8 SAD cdist kernel, kk-paired W (R19) -------------------
// block tile 64 rows x 32 cols, BK=32, 256 threads, 8 blocks/CU.
// X in LDS [kk][row] (b128 broadcast reads, 16 lanes/addr). W in LDS
// kk-PAIRED: [kkp][c*68 + col*2 + (kk&1)] — staged by one ds_write_b64,
// read by one b128 per c per kk-pair (2 kks x 2 cols). Double-buffered,
// ONE barrier per k0. Inner ds_reads/k0: 8 X + 4*NCD W.
// EPI 1: QKV, blockIdx.z = {0:q, 1:k, 2:v}; q,k -> tanh u8, v -> f16 transposed.
// EPI 2: gate/val (NCD=2) -> tanh(silu(g)*v) u8.
// EPI 3: split-K partial (blockIdx.z = K-slice) -> u16 plain stores into
//        contiguous pf (slice stride NROWS*M u16); (acc+1)>>1 fits u16 at
//        Kc=512 (max 130560/2); rounding err <= 2 counts total.
template <int NCD, int EPI>
__global__ __launch_bounds__(256, 8) void cdistq_kernel(
    const unsigned char* __restrict__ X8, const unsigned char* __restrict__ W8,
    CP cp,
    unsigned char* __restrict__ o8a, unsigned char* __restrict__ o8b,
    hf* __restrict__ vt16, unsigned char* __restrict__ gvt8,
    unsigned short* __restrict__ pf,
    int M, int K, int Kc, float invK127)
{
  const int m0 = blockIdx.x * 32, n0 = blockIdx.y * 64;
  const int zc = (EPI == 1) ? blockIdx.z : 0;          // QKV: z picks cdist
  const int kb = (EPI == 3) ? blockIdx.z * Kc : 0;     // split-K slice
  constexpr int WROW = NCD * 68 + 4;
  __shared__ __align__(16) unsigned xs[2][8][68];      // [dbuf][kk][row]
  __shared__ __align__(16) unsigned ws[2][4][WROW];    // [dbuf][kkp][c*68+col*2+half]
  const int tid = threadIdx.x, tx = tid & 15, ty = tid >> 4;
  unsigned acc[NCD][4][2] = {};

  // X staging: row rs, kk dwords ps..ps+1
  const int rs = tid >> 2, ps = (tid & 3) * 2;
  // W staging: 128 threads per c; col wcol, kk dwords pw..pw+1 (same kkp)
  const int half = tid & 127;
  const int wc = (NCD == 2) ? (tid >> 7) : 0;
  const int wcol = half >> 2, pw = (half & 3) * 2;

  const unsigned char* xp = X8 + (size_t)(n0 + rs) * K + kb + (tid & 3) * 8;
  const unsigned char* wq = W8 + (size_t)(zc + wc) * M * K +
                            (size_t)(m0 + wcol) * K + kb + (half & 3) * 8;

  uint2 xv = *(const uint2*)xp;
  uint2 wv = *(const uint2*)wq;

  int p = 0;
#pragma unroll 1
  for (int k0 = 0; k0 < Kc; k0 += 32) {
    // stage current tile from regs (one barrier per k0; dbuf keeps next-iter
    // writes off the buffer still being read)
    xs[p][ps + 0][rs] = xv.x;
    xs[p][ps + 1][rs] = xv.y;
    *(uint2*)&ws[p][pw >> 1][wc * 68 + wcol * 2] = make_uint2(wv.x, wv.y);
    // prefetch next k-slab into regs (dummy re-read of 0 on last iter)
    const int kn = (k0 + 32 < Kc) ? k0 + 32 : 0;
    xv = *(const uint2*)(xp + kn);
    wv = *(const uint2*)(wq + kn);
    __syncthreads();

#pragma unroll
    for (int kkp = 0; kkp < 4; kkp++) {
      uint4 a0 = *(const uint4*)&xs[p][kkp * 2 + 0][ty * 4];
      uint4 a1 = *(const uint4*)&xs[p][kkp * 2 + 1][ty * 4];
      const unsigned ae[4] = {a0.x, a0.y, a0.z, a0.w};
      const unsigned ao[4] = {a1.x, a1.y, a1.z, a1.w};
#pragma unroll
      for (int c = 0; c < NCD; c++) {
        // b4 = {col0@kk_even, col0@kk_odd, col1@kk_even, col1@kk_odd}
        uint4 b4 = *(const uint4*)&ws[p][kkp][c * 68 + tx * 4];
#pragma unroll
        for (int i = 0; i < 4; i++) {
          acc[c][i][0] = sad8(ae[i], b4.x, acc[c][i][0]);
          acc[c][i][0] = sad8(ao[i], b4.y, acc[c][i][0]);
          acc[c][i][1] = sad8(ae[i], b4.z, acc[c][i][1]);
          acc[c][i][1] = sad8(ao[i], b4.w, acc[c][i][1]);
        }
      }
    }
    p ^= 1;
  }

  if constexpr (EPI == 1) {                  // QKV, z-selected cdist (NCD=1)
    if (zc < 2) {                            // q or k -> tanh u8
      unsigned char* o8 = zc ? o8b : o8a;
      const float* gn = zc ? cp.g1 : cp.g0;
#pragma unroll
      for (int i = 0; i < 4; i++) {
        const int n = n0 + ty * 4 + i;
        unsigned pk = 0;
#pragma unroll
        for (int j = 0; j < 2; j++) {
          const int m = m0 + tx * 2 + j;
          const float val = (0.5f - (float)acc[0][i][j] * invK127) * gn[m];
          pk |= q8(ftanh(val)) << (8 * j);
        }
        *(unsigned short*)&o8[(size_t)n * M + m0 + tx * 2] = (unsigned short)pk;
      }
    } else {                                 // v -> f16 transposed [bh][d][t]
#pragma unroll
      for (int i = 0; i < 4; i++) {
        const int n = n0 + ty * 4 + i;
        const int b = n >> 10, t = n & 1023;
#pragma unroll
        for (int j = 0; j < 2; j++) {
          const int m = m0 + tx * 2 + j;
          const float vv = (0.5f - (float)acc[0][i][j] * invK127) * cp.g2[m];
          vt16[((size_t)(b * 8 + (m >> 6)) * 64 + (m & 63)) * 1024 + t] = (hf)vv;
        }
      }
    }
  } else if constexpr (EPI == 2) {           // gate/val: NCD=2
#pragma unroll
    for (int i = 0; i < 4; i++) {
      const int n = n0 + ty * 4 + i;
      unsigned pk = 0;
#pragma unroll
      for (int j = 0; j < 2; j++) {
        const int m = m0 + tx * 2 + j;
        float g = (0.5f - (float)acc[0][i][j] * invK127) * cp.g0[m];
        g = g / (1.0f + __expf(-g));         // silu
        const float vv = (0.5f - (float)acc[1][i][j] * invK127) * cp.g1[m];
        pk |= q8(ftanh(g * vv)) << (8 * j);
      }
      *(unsigned short*)&gvt8[(size_t)n * M + m0 + tx * 2] = (unsigned short)pk;
    }
  } else {                                   // EPI==3: u16 partials, plain stores
    unsigned short* pz = pf + (size_t)blockIdx.z * ((size_t)NROWS * M);
#pragma unroll
    for (int i = 0; i < 4; i++) {
      const int n = n0 + ty * 4 + i;
      const unsigned p0 = (acc[0][i][0] + 1) >> 1;
      const unsigned p1 = (acc[0][i][1] + 1) >> 1;
      *(unsigned*)&pz[(size_t)n * M + m0 + tx * 2] = p0 | (p1 << 16);
    }
  }
}

// ---------------- attention: split-S partial (u8 SAD QK, MFMA PV) ----------
// grid (144, 16): chunk = (tt, <=2 s-tiles). Per bh: sum ceil((tt/2+1)/2) = 144.
__global__ __launch_bounds__(256) void attn_part_kernel(
    const unsigned char* __restrict__ Qb, const unsigned char* __restrict__ Kb,
    const hf* __restrict__ Vt,
    const float* __restrict__ gamma, const float* __restrict__ rho,
    float* __restrict__ accO, float* __restrict__ accR)
{
  const int bh = blockIdx.y, b = bh >> 3, h = bh & 7;
  int rem = 143 - (int)blockIdx.x;              // heavy (high-tt) chunks first
  int tt = 0;
  for (;;) {
    const int nc = ((tt >> 1) + 2) >> 1;        // ceil((tt/2+1)/2)
    if (rem < nc) break;
    rem -= nc; ++tt;
  }
  const int ntile = (tt >> 1) + 1;
  const int sb = rem * 2;
  const int se = (sb + 2 < ntile) ? sb + 2 : ntile;
  const int t0 = tt * 32;

  const float gp = log1pf(expf(gamma[h]));
  const float nrp = -log1pf(expf(rho[h]));      // -rho softplus (pow exponent)
  const size_t base8 = ((size_t)b * TSEQ) * DMODEL + h * 64;

  __shared__ unsigned qs8[16][36];   // [kk4][t]
  __shared__ unsigned ks8[16][68];   // [kk4][s]
  __shared__ hf awt[32][72];         // AW [t][s] row-major (+pad)
  __shared__ hf vsm[64][72];         // V  [d][s] row-major (+pad)

  const int tid = threadIdx.x, tx = tid & 15, ty = tid >> 4;
  const int tx4 = tx * 4, ty2 = ty * 2;
  const int lane = tid & 63, wv = tid >> 6;
  const float SCALE_D = 1.0f / (127.5f * 8.0f);   // sad -> l1/Dh*sqrt(Dh)

  {  // Q tile 32x64 u8, transposed into dword-rows
    const int r = tid >> 3, p = (tid & 7) * 2;
    uint2 a = *(const uint2*)&Qb[base8 + (size_t)(t0 + r) * DMODEL + (tid & 7) * 8];
    qs8[p + 0][r] = a.x;
    qs8[p + 1][r] = a.y;
  }

  float rsum[2] = {};
  f32x4 cacc[2] = {};                // MFMA accumulators: [mtile] x 4 f32

  const int vd = tid >> 2, vs16 = (tid & 3) * 16;
  const int arow = lane & 15;        // MFMA m/n index
  const int koff = (lane >> 4) * 8;  // MFMA k sub-offset

  for (int st = sb; st < se; ++st) {
    const int s0 = st * 64;
    __syncthreads();
    {  // K tile 64x64 u8 (transposed dwords)
      const int r = tid >> 2, p = (tid & 3) * 4;
      uint4 a = *(const uint4*)&Kb[base8 + (size_t)(s0 + r) * DMODEL + (tid & 3) * 16];
      ks8[p + 0][r] = a.x;
      ks8[p + 1][r] = a.y;
      ks8[p + 2][r] = a.z;
      ks8[p + 3][r] = a.w;
      // V tile: transposed f16 in HBM -> plain [d][s] rows in LDS
      const hf* vsrc = &Vt[((size_t)bh * 64 + vd) * 1024 + s0 + vs16];
      *(h8*)&vsm[vd][vs16 + 0] = *(const h8*)vsrc;
      *(h8*)&vsm[vd][vs16 + 8] = *(const h8*)(vsrc + 8);
    }
    __syncthreads();

    // L1 via v_sad_u8 (exact integer)
    unsigned sacc[2][4] = {};
#pragma unroll
    for (int kk = 0; kk < 16; kk++) {
      uint2 qa = *(const uint2*)&qs8[kk][ty2];
      uint4 kb4 = *(const uint4*)&ks8[kk][tx4];
      const unsigned kk4[4] = {kb4.x, kb4.y, kb4.z, kb4.w};
#pragma unroll
      for (int j = 0; j < 4; j++) {
        sacc[0][j] = sad8(qa.x, kk4[j], sacc[0][j]);
        sacc[1][j] = sad8(qa.y, kk4[j], sacc[1][j]);
      }
    }

    // kernel weights + causal mask -> f16 [t][s] in LDS
#pragma unroll
    for (int i = 0; i < 2; i++) {
      const int tg = t0 + ty2 + i;
      h4 pk;
#pragma unroll
      for (int j = 0; j < 4; j++) {
        const int sg = s0 + tx4 + j;
        const float dist = (float)sacc[i][j] * SCALE_D;
        const float bsx = fmaf(gp, dist * dist, 1.0f + 1e-6f);
        float aw = fpow_ge1(bsx, nrp);              // bsx>=1: raw log/exp
        aw = (sg <= tg) ? aw : 0.0f;
        pk[j] = (hf)aw;
        rsum[i] += aw;
      }
      *(h4*)&awt[ty2 + i][tx4] = pk;
    }
    __syncthreads();

    // PV: O[32x64] += AW[32x64] @ V[64x64] via MFMA (wave wv owns d-cols 16wv..)
#ifdef HAVE_MFMA
#pragma unroll
    for (int ks = 0; ks < 2; ks++) {
      h8 bfrag = *(const h8*)&vsm[wv * 16 + arow][ks * 32 + koff];
      h8 afr0  = *(const h8*)&awt[arow]          [ks * 32 + koff];
      h8 afr1  = *(const h8*)&awt[16 + arow]     [ks * 32 + koff];
      cacc[0] = __builtin_amdgcn_mfma_f32_16x16x32_f16(afr0, bfrag, cacc[0], 0, 0, 0);
      cacc[1] = __builtin_amdgcn_mfma_f32_16x16x32_f16(afr1, bfrag, cacc[1], 0, 0, 0);
    }
#else
    {
      const int crow = (lane >> 4) * 4;
      const int d = wv * 16 + (lane & 15);
#pragma unroll
      for (int mt = 0; mt < 2; mt++)
#pragma unroll
        for (int r = 0; r < 4; r++) {
          const int t = mt * 16 + crow + r;
          float s = cacc[mt][r];
          for (int si = 0; si < 64; si++)
            s += (float)awt[t][si] * (float)vsm[d][si];
          cacc[mt][r] = s;
        }
    }
#endif
  }

#pragma unroll
  for (int off = 1; off < 16; off <<= 1) {
    rsum[0] += __shfl_xor(rsum[0], off);
    rsum[1] += __shfl_xor(rsum[1], off);
  }
  float* aO = accO + ((size_t)bh * TSEQ + t0) * 64;
  {   // C/D layout: col=lane&15 (d), row=(lane>>4)*4+reg (t)
    const int crow = (lane >> 4) * 4;
    const int ccol = wv * 16 + (lane & 15);
#pragma unroll
    for (int mt = 0; mt < 2; mt++)
#pragma unroll
      for (int r = 0; r < 4; r++)
        atomicAdd(&aO[(size_t)(mt * 16 + crow + r) * 64 + ccol], cacc[mt][r]);
  }
#pragma unroll
  for (int i = 0; i < 2; i++)
    if (tx == 0) atomicAdd(&accR[bh * TSEQ + t0 + ty2 + i], rsum[i]);
}

// ---------------- wo GEMM + residual, attn-normalize fused in staging ------
// Xn = accO [bh][1024][64]; logical attn[n][c] = Xn[bh(n,c)][t(n)][c&63]/rsum.
__global__ __launch_bounds__(256) void gemm_res_kernel(
    const float* __restrict__ Xn, const float* __restrict__ accR,
    const float* __restrict__ W,
    const float* __restrict__ bias, const float* __restrict__ Res,
    float* __restrict__ Out)
{
  const int m0 = blockIdx.x * 64, n0 = blockIdx.y * 64;
  __shared__ float xs[16][68];
  __shared__ float wsm[16][68];
  const int tid = threadIdx.x, tx = tid & 15, ty = tid >> 4;
  const int lr = tid >> 2, lc4 = (tid & 3) * 4;
  float acc[4][4] = {};
  const int n = n0 + lr;
  const float* wp = &W[(size_t)(m0 + lr) * DMODEL + lc4];
  for (int k0 = 0; k0 < DMODEL; k0 += 16) {
    const int c = k0 + lc4;
    const size_t arow = ((size_t)((n >> 10) * 8 + (c >> 6))) * TSEQ + (n & 1023);
    float4 xv = *(const float4*)&Xn[arow * 64 + (c & 63)];
    const float inv = 1.0f / (accR[arow] + 1e-6f);
    xv.x *= inv; xv.y *= inv; xv.z *= inv; xv.w *= inv;
    float4 wv = *(const float4*)(wp + k0);
    __syncthreads();
    xs [lc4 + 0][lr] = xv.x; xs [lc4 + 1][lr] = xv.y; xs [lc4 + 2][lr] = xv.z; xs [lc4 + 3][lr] = xv.w;
    wsm[lc4 + 0][lr] = wv.x; wsm[lc4 + 1][lr] = wv.y; wsm[lc4 + 2][lr] = wv.z; wsm[lc4 + 3][lr] = wv.w;
    __syncthreads();
#pragma unroll
    for (int kk = 0; kk < 16; kk++) {
      float4 av = *(const float4*)&xs[kk][ty * 4];
      float4 bv = *(const float4*)&wsm[kk][tx * 4];
      const float aa[4] = {av.x, av.y, av.z, av.w};
      const float bs[4] = {bv.x, bv.y, bv.z, bv.w};
#pragma unroll
      for (int i = 0; i < 4; i++)
#pragma unroll
        for (int j = 0; j < 4; j++) acc[i][j] = fmaf(aa[i], bs[j], acc[i][j]);
    }
  }
#pragma unroll
  for (int i = 0; i < 4; i++) {
    const int nn = n0 + ty * 4 + i;
    float o[4];
#pragma unroll
    for (int j = 0; j < 4; j++) {
      const int m = m0 + tx * 4 + j;
      o[j] = acc[i][j] + bias[m] + Res[(size_t)nn * DMODEL + m];
    }
    *(float4*)&Out[(size_t)nn * DMODEL + m0 + tx * 4] = make_float4(o[0], o[1], o[2], o[3]);
  }
}

// ---------------- final combine (fused out-proxy epilogue) ------------------
// out = x2 + f + 0.5*|shift(h) - sigmoid(dir_w)|, f from u16 split-K partials
// (each partial = round(acc_z/2); sum of 4 slices, scale 2x folded into invf).
__global__ void final_kernel(const float* __restrict__ x2,
                             const unsigned short* __restrict__ pf,
                             const float* __restrict__ outg,
                             const float* __restrict__ h,
                             const float* __restrict__ dirw,
                             float* __restrict__ out)
{
  const int i4 = blockIdx.x * 256 + threadIdx.x;
  const int n = i4 >> 7;
  const int t = n & (TSEQ - 1);
  const int d4 = (i4 & 127) * 4;
  float4 xv = *(const float4*)&x2[(size_t)i4 * 4];
  const size_t off = (size_t)i4 * 4;
  unsigned s[4] = {};
#pragma unroll
  for (int z = 0; z < 4; z++) {
    uint2 a = *(const uint2*)&pf[(size_t)z * ((size_t)NROWS * DMODEL) + off];
    s[0] += (a.x & 0xffffu);
    s[1] += (a.x >> 16);
    s[2] += (a.y & 0xffffu);
    s[3] += (a.y >> 16);
  }
  float4 hv = make_float4(0.f, 0.f, 0.f, 0.f);
  if (t != 0) hv = *(const float4*)&h[(size_t)(i4 - 128) * 4];
  const float xx[4] = {xv.x, xv.y, xv.z, xv.w};
  const float hh[4] = {hv.x, hv.y, hv.z, hv.w};
  const float invf = 2.0f / (127.5f * 2048.0f);   // 2x: partials store acc/2
  float o[4];
#pragma unroll
  for (int j = 0; j < 4; j++) {
    const float f = (0.5f - (float)s[j] * invf) * outg[d4 + j];
    const float sg = 1.0f / (1.0f + __expf(-dirw[d4 + j]));
    o[j] = xx[j] + f + 0.5f * fabsf(hh[j] - sg);
  }
  *(float4*)&out[(size_t)i4 * 4] = make_float4(o[0], o[1], o[2], o[3]);
}

// ---------------------------------------------------------------------------
extern "C" void kernel_launch(void* const* d_in, const int* in_sizes, int n_in,
                              void* d_out, int out_size, void* d_ws, size_t ws_size,
                              hipStream_t stream)
{
  (void)in_sizes; (void)n_in; (void)out_size;
  const float* x      = (const float*)d_in[0];
  const float* ln1_w  = (const float*)d_in[1];
  const float* ln1_b  = (const float*)d_in[2];
  const float* wq_w   = (const float*)d_in[3];
  const float* wq_g   = (const float*)d_in[4];
  const float* wk_w   = (const float*)d_in[5];
  const float* wk_g   = (const float*)d_in[6];
  const float* wv_w   = (const float*)d_in[7];
  const float* wv_g   = (const float*)d_in[8];
  const float* wo_w   = (const float*)d_in[9];
  const float* wo_b   = (const float*)d_in[10];
  const float* gamma  = (const float*)d_in[11];
  const float* rho    = (const float*)d_in[12];
  const float* ln2_w  = (const float*)d_in[13];
  const float* ln2_b  = (const float*)d_in[14];
  const float* gate_w = (const float*)d_in[15];
  const float* gate_g = (const float*)d_in[16];
  const float* val_w  = (const float*)d_in[17];
  const float* val_g  = (const float*)d_in[18];
  const float* out_w  = (const float*)d_in[19];
  const float* out_g  = (const float*)d_in[20];
  const float* dir_w  = (const float*)d_in[21];
  float* out = (float*)d_out;

  if (ws_size < ((size_t)32 << 20)) return;
  unsigned char* wsb = (unsigned char*)d_ws;

  unsigned char* w8   = wsb;                          // [0,2MB) weights u8
  unsigned char* x8   = wsb + ((size_t)2 << 20);      // xt8; later ht8
  unsigned char* q8b  = wsb + ((size_t)3 << 20);
  unsigned char* k8b  = wsb + ((size_t)4 << 20);
  hf*            vt16 = (hf*)(wsb + ((size_t)5 << 20));       // 2MB
  unsigned char* gvt8 = wsb + ((size_t)7 << 20);              // 4MB
  float*         accO = (float*)(wsb + ((size_t)11 << 20));   // 4MB
  float*         accR = (float*)(wsb + ((size_t)15 << 20));   // 64KB (contig w/ accO)
  unsigned short* pf  = (unsigned short*)(wsb + ((size_t)16 << 20)); // 8MB, 4 u16 slices
  float*         x2   = (float*)(wsb + ((size_t)24 << 20));   // 4MB
  float*         hbuf = (float*)(wsb + ((size_t)28 << 20));   // 4MB

  // 1. xt8 = q8(tanh(LN1(x))); also zeroes accO+accR (130 float4/block)
  ln_kernel<<<NROWS, 256, 0, stream>>>(x, ln1_w, ln1_b, nullptr, x8,
                                       (float4*)accO);

  // 2. q/k/v weights -> tanh u8 (one fused dispatch, z-indexed)
  tanhcvt8m_kernel<<<dim3(256, 3), 256, 0, stream>>>(wq_w, wk_w, wv_w, w8, 512);

  // 3. q,k,v cdists (SAD), z-split; q/k -> u8, v -> f16 transposed
  {
    CP cp; cp.g0 = wq_g; cp.g1 = wk_g; cp.g2 = wv_g;
    cdistq_kernel<1, 1><<<dim3(16, 32, 3), 256, 0, stream>>>(
        x8, w8, cp, q8b, k8b, vt16, nullptr, nullptr,
        512, 512, 512, 1.0f / (127.5f * 512.0f));
  }

  // 4. attention: split-S partial (accO/accR pre-zeroed by step 1)
  attn_part_kernel<<<dim3(144, 16), 256, 0, stream>>>(q8b, k8b, vt16,
                                                      gamma, rho, accO, accR);

  // 5. x2 = x + normalize(accO/accR) @ wo^T + wo_b  (normalize fused)
  gemm_res_kernel<<<dim3(8, 32), 256, 0, stream>>>(accO, accR, wo_w, wo_b, x, x2);

  // 6. h (f32) + ht8 = LN2(x2)
  ln_kernel<<<NROWS, 256, 0, stream>>>(x2, ln2_w, ln2_b, hbuf, x8, nullptr);

  // 7. gate/val weights -> tanh u8 (one fused dispatch)
  tanhcvt8m_kernel<<<dim3(1024, 2), 256, 0, stream>>>(gate_w, val_w, val_w, w8, 512);

  // 8. gvt8 = q8(tanh(silu(gate)*val)), kk-paired: 2048 blocks, 8/CU
  {
    CP cp; cp.g0 = gate_g; cp.g1 = val_g; cp.g2 = nullptr;
    cdistq_kernel<2, 2><<<dim3(64, 32, 1), 256, 0, stream>>>(
        x8, w8, cp, nullptr, nullptr, nullptr, gvt8, nullptr,
        2048, 512, 512, 1.0f / (127.5f * 512.0f));
  }

  // 9. out_w -> tanh u8 (512 rows, K=2048)
  tanhcvt8m_kernel<<<dim3(256, 1), 256, 0, stream>>>(out_w, out_w, out_w, w8, 2048);

  // 10. out-proxy partial sums (K=2048): kk-paired, split-K=4, u16 plain
  //     stores (no memset, no atomics). 2048 blocks -> 8/CU.
  {
    CP cp; cp.g0 = out_g; cp.g1 = nullptr; cp.g2 = nullptr;
    cdistq_kernel<1, 3><<<dim3(16, 32, 4), 256, 0, stream>>>(
        gvt8, w8, cp, nullptr, nullptr, nullptr, nullptr, pf,
        512, 2048, 512, 0.0f);
  }

  // 11. out = x2 + f(partials) + 0.5*|shift(h) - sigmoid(dir_w)|  (fepi fused)
  final_kernel<<<1024, 256, 0, stream>>>(x2, pf, out_g, hbuf, dir_w, out);
}

// Round 9
// 150.833 us; speedup vs baseline: 2.6030x; 1.0615x over previous
//
#include <hip/hip_runtime.h>
#include <math.h>

// DeltaBlock forward, MI355X. All proxy layers / attention distances are L1-cdists
// (stop_gradient(l1-l2)+l2 == l1 forward). R7: u8 v_sad_u8 cdists (exact).
// R8: attention PV via mfma_f32_16x16x32_f16. R9/R10: occupancy + fusion.
// R11: transcendental diet. R12: u16 split-K partials. R13-R18: tile/staging
// sweep — conclusion: cdist is VALU-issue-dominated (SAD half-rate floor
// ~27us for step 8); LDS reads, barriers, occupancy each worth only 1-3us.
// R19: kk-paired W (best: 160.1us, step8 47.4 @ VALUBusy 72%).
// R20: (a) BK=64 — two k-slabs per barrier, halves barrier-convoy count,
// doubles latency-hiding run length; (b) dispatch merges 11 -> 8: step 2
// folded into step 1 (flat grid, block-level branch), steps 7+9 folded into
// step 6 (step-9 u8 weights -> dead vt16 region at +5MB, no w8 aliasing).

#define NROWS  2048
#define DMODEL 512
#define TSEQ   1024
#define HIDDEN 2048

typedef _Float16 hf;
typedef hf h2 __attribute__((ext_vector_type(2)));
typedef hf h4 __attribute__((ext_vector_type(4)));
typedef hf h8 __attribute__((ext_vector_type(8)));
typedef float f32x4 __attribute__((ext_vector_type(4)));

#if defined(__has_builtin)
#if __has_builtin(__builtin_amdgcn_sad_u8)
#define HAVE_SAD 1
#endif
#if __has_builtin(__builtin_amdgcn_mfma_f32_16x16x32_f16)
#define HAVE_MFMA 1
#endif
#endif

__device__ __forceinline__ unsigned sad8(unsigned a, unsigned b, unsigned c) {
#ifdef HAVE_SAD
  return __builtin_amdgcn_sad_u8(a, b, c);
#else
  unsigned r;
  asm("v_sad_u8 %0, %1, %2, %3" : "=v"(r) : "v"(a), "v"(b), "v"(c));
  return r;
#endif
}

// fast tanh: sign(x)*(1-t)/(1+t), t=e^(-2|x|); err ~1e-7 << q8 step 4e-3
__device__ __forceinline__ float ftanh(float x) {
  const float t = __expf(-2.0f * fabsf(x));
  const float r = (1.0f - t) / (1.0f + t);
  return copysignf(r, x);
}

// x^p for x>=1 (no edge cases): exp2(p*log2(x)) via raw v_log/v_exp
__device__ __forceinline__ float fpow_ge1(float x, float p) {
  float lg, r;
  asm("v_log_f32 %0, %1" : "=v"(lg) : "v"(x));
  const float e = lg * p;
  asm("v_exp_f32 %0, %1" : "=v"(r) : "v"(e));
  return r;
}

__device__ __forceinline__ unsigned q8(float x) {   // tanh-range (-1,1) -> u8
  return (unsigned)(int)((x + 1.0f) * 127.5f + 0.5f);
}

struct CP { const float* g0; const float* g1; const float* g2; };

// ---------------- device bodies for fused dispatches -----------------------
// LayerNorm row n: f32 row -> (optional f32 out) + tanh-u8 out; optional
// zero-fill of accO/accR (130 float4 per block, exact).
__device__ __forceinline__ void ln_body(
    int n, const float* __restrict__ X, const float* __restrict__ w,
    const float* __restrict__ bb, float* __restrict__ outPlain,
    unsigned char* __restrict__ out8, float4* __restrict__ zf)
{
  const int tid = threadIdx.x;
  if (zf && tid < 130)
    zf[(size_t)n * 130 + tid] = make_float4(0.f, 0.f, 0.f, 0.f);
  const float* row = X + (size_t)n * DMODEL;
  float2 v = *(const float2*)&row[tid * 2];
  float s1 = v.x + v.y;
  float s2 = v.x * v.x + v.y * v.y;
#pragma unroll
  for (int off = 1; off < 64; off <<= 1) {
    s1 += __shfl_xor(s1, off);
    s2 += __shfl_xor(s2, off);
  }
  __shared__ float red[8];
  if ((tid & 63) == 0) { red[(tid >> 6) * 2] = s1; red[(tid >> 6) * 2 + 1] = s2; }
  __syncthreads();
  s1 = red[0] + red[2] + red[4] + red[6];
  s2 = red[1] + red[3] + red[5] + red[7];
  const float mu   = s1 * (1.0f / DMODEL);
  const float var  = s2 * (1.0f / DMODEL) - mu * mu;
  const float rstd = rsqrtf(var + 1e-5f);
  const int d = tid * 2;
  const float y0 = (v.x - mu) * rstd * w[d]     + bb[d];
  const float y1 = (v.y - mu) * rstd * w[d + 1] + bb[d + 1];
  if (outPlain) *(float2*)&outPlain[(size_t)n * DMODEL + d] = make_float2(y0, y1);
  const unsigned a = q8(ftanh(y0)), b = q8(ftanh(y1));
  *(unsigned short*)&out8[(size_t)n * DMODEL + d] = (unsigned short)(a | (b << 8));
}

// tanh+q8 of one f32 row (128 threads of the half-block given by tid>>7)
__device__ __forceinline__ void cvt_body(
    const float* __restrict__ src, unsigned char* __restrict__ dst, int K)
{
  const int t = threadIdx.x & 127;
  for (int k = t * 4; k < K; k += 512) {
    float4 v = *(const float4*)&src[k];
    unsigned pk = q8(ftanh(v.x)) | (q8(ftanh(v.y)) << 8) |
                  (q8(ftanh(v.z)) << 16) | (q8(ftanh(v.w)) << 24);
    *(unsigned*)&dst[k] = pk;
  }
}

// ---------------- fused step 1+2: LN1 + q/k/v weight cvt -------------------
// grid 2048 + 768: b<2048 -> ln row b (zeroes accO/accR); else qkv-weight cvt.
__global__ __launch_bounds__(256) void fused1_kernel(
    const float* __restrict__ X, const float* __restrict__ lw,
    const float* __restrict__ lb, unsigned char* __restrict__ x8,
    float4* __restrict__ zf,
    const float* __restrict__ wq, const float* __restrict__ wk,
    const float* __restrict__ wv, unsigned char* __restrict__ w8)
{
  const int b = blockIdx.x;
  if (b < NROWS) { ln_body(b, X, lw, lb, nullptr, x8, zf); return; }
  const int c = b - NROWS;                       // [0, 768)
  const int z = c >> 8, rb = c & 255;
  const float* sb = (z == 0) ? wq : (z == 1) ? wk : wv;
  const int row = rb * 2 + (threadIdx.x >> 7);   // 512 rows per z
  cvt_body(sb + (size_t)row * 512, w8 + ((size_t)z * 512 + row) * 512, 512);
}

// ---------------- fused step 6+7+9: LN2 + gate/val cvt + out_w cvt ---------
// grid 2048 + 2048 + 256. out_w u8 goes to w9 (separate region, no w8 alias).
__global__ __launch_bounds__(256) void fused6_kernel(
    const float* __restrict__ x2, const float* __restrict__ lw,
    const float* __restrict__ lb, float* __restrict__ hbuf,
    unsigned char* __restrict__ x8,
    const float* __restrict__ gate_w, const float* __restrict__ val_w,
    unsigned char* __restrict__ w8,
    const float* __restrict__ out_w, unsigned char* __restrict__ w9)
{
  const int b = blockIdx.x;
  if (b < NROWS) { ln_body(b, x2, lw, lb, hbuf, x8, nullptr); return; }
  int c = b - NROWS;
  if (c < 2048) {                                // gate/val: 2048 rows per z
    const int z = c >> 10, rb = c & 1023;
    const float* sb = z ? val_w : gate_w;
    const int row = rb * 2 + (threadIdx.x >> 7);
    cvt_body(sb + (size_t)row * 512, w8 + ((size_t)z * 2048 + row) * 512, 512);
  } else {                                       // out_w: 512 rows, K=2048
    c -= 2048;                                   // [0, 256)
    const int row = c * 2 + (threadIdx.x >> 7);
    cvt_body(out_w + (size_t)row * 2048, w9 + (size_t)row * 2048, 2048);
  }
}

// ---------------- u8 SAD cdist kernel, kk-paired W, BK=64 (R20) ------------
// block tile 64 rows x 32 cols, BK=64 (two 32B slabs per barrier), 256
// threads, 8 blocks/CU. X in LDS [kk][row] (b128 broadcast reads). W in LDS
// kk-PAIRED [kkp][c*68 + col*2 + (kk&1)] — one ds_write_b64 stages 2 kks;
// one b128 read serves 2 kks x 2 cols. Double-buffered, ONE barrier per 64B
// of K. Inner ds_reads per 64B: 16 X + 8*NCD W for 256*NCD sads.
// EPI 1: QKV, blockIdx.z = {0:q, 1:k, 2:v}; q,k -> tanh u8, v -> f16 transposed.
// EPI 2: gate/val (NCD=2) -> tanh(silu(g)*v) u8.
// EPI 3: split-K partial (blockIdx.z = K-slice) -> u16 plain stores into
//        contiguous pf (slice stride NROWS*M u16); (acc+1)>>1 fits u16 at
//        Kc=512 (max 130560/2); rounding err <= 2 counts total.
template <int NCD, int EPI>
__global__ __launch_bounds__(256, 8) void cdistq_kernel(
    const unsigned char* __restrict__ X8, const unsigned char* __restrict__ W8,
    CP cp,
    unsigned char* __restrict__ o8a, unsigned char* __restrict__ o8b,
    hf* __restrict__ vt16, unsigned char* __restrict__ gvt8,
    unsigned short* __restrict__ pf,
    int M, int K, int Kc, float invK127)
{
  const int m0 = blockIdx.x * 32, n0 = blockIdx.y * 64;
  const int zc = (EPI == 1) ? blockIdx.z : 0;          // QKV: z picks cdist
  const int kb = (EPI == 3) ? blockIdx.z * Kc : 0;     // split-K slice
  constexpr int WROW = NCD * 68 + 4;
  __shared__ __align__(16) unsigned xs[2][16][68];     // [dbuf][kk][row]
  __shared__ __align__(16) unsigned ws[2][8][WROW];    // [dbuf][kkp][c*68+col*2+half]
  const int tid = threadIdx.x, tx = tid & 15, ty = tid >> 4;
  unsigned acc[NCD][4][2] = {};

  // X staging: row rs, kk dwords ps..ps+1 (per slab)
  const int rs = tid >> 2, ps = (tid & 3) * 2;
  // W staging: 128 threads per c; col wcol, kkp = (half&3) (per slab)
  const int half = tid & 127;
  const int wc = (NCD == 2) ? (tid >> 7) : 0;
  const int wcol = half >> 2, kkw = half & 3;

  const unsigned char* xp = X8 + (size_t)(n0 + rs) * K + kb + (tid & 3) * 8;
  const unsigned char* wq = W8 + (size_t)(zc + wc) * M * K +
                            (size_t)(m0 + wcol) * K + kb + kkw * 8;

  uint2 xv0 = *(const uint2*)xp;
  uint2 xv1 = *(const uint2*)(xp + 32);
  uint2 wv0 = *(const uint2*)wq;
  uint2 wv1 = *(const uint2*)(wq + 32);

  int p = 0;
#pragma unroll 1
  for (int k0 = 0; k0 < Kc; k0 += 64) {
    // stage both slabs from regs (one barrier per 64B; dbuf keeps next-iter
    // writes off the buffer still being read)
    xs[p][ps + 0][rs] = xv0.x;
    xs[p][ps + 1][rs] = xv0.y;
    xs[p][8 + ps + 0][rs] = xv1.x;
    xs[p][8 + ps + 1][rs] = xv1.y;
    *(uint2*)&ws[p][kkw][wc * 68 + wcol * 2]     = make_uint2(wv0.x, wv0.y);
    *(uint2*)&ws[p][4 + kkw][wc * 68 + wcol * 2] = make_uint2(wv1.x, wv1.y);
    // prefetch next k-slabs into regs (dummy re-read of 0 on last iter)
    const int kn = (k0 + 64 < Kc) ? k0 + 64 : 0;
    xv0 = *(const uint2*)(xp + kn);
    xv1 = *(const uint2*)(xp + kn + 32);
    wv0 = *(const uint2*)(wq + kn);
    wv1 = *(const uint2*)(wq + kn + 32);
    __syncthreads();

#pragma unroll
    for (int kkp = 0; kkp < 8; kkp++) {
      uint4 a0 = *(const uint4*)&xs[p][kkp * 2 + 0][ty * 4];
      uint4 a1 = *(const uint4*)&xs[p][kkp * 2 + 1][ty * 4];
      const unsigned ae[4] = {a0.x, a0.y, a0.z, a0.w};
      const unsigned ao[4] = {a1.x, a1.y, a1.z, a1.w};
#pragma unroll
      for (int c = 0; c < NCD; c++) {
        // b4 = {col0@kk_even, col0@kk_odd, col1@kk_even, col1@kk_odd}
        uint4 b4 = *(const uint4*)&ws[p][kkp][c * 68 + tx * 4];
#pragma unroll
        for (int i = 0; i < 4; i++) {
          acc[c][i][0] = sad8(ae[i], b4.x, acc[c][i][0]);
          acc[c][i][0] = sad8(ao[i], b4.y, acc[c][i][0]);
          acc[c][i][1] = sad8(ae[i], b4.z, acc[c][i][1]);
          acc[c][i][1] = sad8(ao[i], b4.w, acc[c][i][1]);
        }
      }
    }
    p ^= 1;
  }

  if constexpr (EPI == 1) {                  // QKV, z-selected cdist (NCD=1)
    if (zc < 2) {                            // q or k -> tanh u8
      unsigned char* o8 = zc ? o8b : o8a;
      const float* gn = zc ? cp.g1 : cp.g0;
#pragma unroll
      for (int i = 0; i < 4; i++) {
        const int n = n0 + ty * 4 + i;
        unsigned pk = 0;
#pragma unroll
        for (int j = 0; j < 2; j++) {
          const int m = m0 + tx * 2 + j;
          const float val = (0.5f - (float)acc[0][i][j] * invK127) * gn[m];
          pk |= q8(ftanh(val)) << (8 * j);
        }
        *(unsigned short*)&o8[(size_t)n * M + m0 + tx * 2] = (unsigned short)pk;
      }
    } else {                                 // v -> f16 transposed [bh][d][t]
#pragma unroll
      for (int i = 0; i < 4; i++) {
        const int n = n0 + ty * 4 + i;
        const int b = n >> 10, t = n & 1023;
#pragma unroll
        for (int j = 0; j < 2; j++) {
          const int m = m0 + tx * 2 + j;
          const float vv = (0.5f - (float)acc[0][i][j] * invK127) * cp.g2[m];
          vt16[((size_t)(b * 8 + (m >> 6)) * 64 + (m & 63)) * 1024 + t] = (hf)vv;
        }
      }
    }
  } else if constexpr (EPI == 2) {           // gate/val: NCD=2
#pragma unroll
    for (int i = 0; i < 4; i++) {
      const int n = n0 + ty * 4 + i;
      unsigned pk = 0;
#pragma unroll
      for (int j = 0; j < 2; j++) {
        const int m = m0 + tx * 2 + j;
        float g = (0.5f - (float)acc[0][i][j] * invK127) * cp.g0[m];
        g = g / (1.0f + __expf(-g));         // silu
        const float vv = (0.5f - (float)acc[1][i][j] * invK127) * cp.g1[m];
        pk |= q8(ftanh(g * vv)) << (8 * j);
      }
      *(unsigned short*)&gvt8[(size_t)n * M + m0 + tx * 2] = (unsigned short)pk;
    }
  } else {                                   // EPI==3: u16 partials, plain stores
    unsigned short* pz = pf + (size_t)blockIdx.z * ((size_t)NROWS * M);
#pragma unroll
    for (int i = 0; i < 4; i++) {
      const int n = n0 + ty * 4 + i;
      const unsigned p0 = (acc[0][i][0] + 1) >> 1;
      const unsigned p1 = (acc[0][i][1] + 1) >> 1;
      *(unsigned*)&pz[(size_t)n * M + m0 + tx * 2] = p0 | (p1 << 16);
    }
  }
}

// ---------------- attention: split-S partial (u8 SAD QK, MFMA PV) ----------
// grid (144, 16): chunk = (tt, <=2 s-tiles). Per bh: sum ceil((tt/2+1)/2) = 144.
__global__ __launch_bounds__(256) void attn_part_kernel(
    const unsigned char* __restrict__ Qb, const unsigned char* __restrict__ Kb,
    const hf* __restrict__ Vt,
    const float* __restrict__ gamma, const float* __restrict__ rho,
    float* __restrict__ accO, float* __restrict__ accR)
{
  const int bh = blockIdx.y, b = bh >> 3, h = bh & 7;
  int rem = 143 - (int)blockIdx.x;              // heavy (high-tt) chunks first
  int tt = 0;
  for (;;) {
    const int nc = ((tt >> 1) + 2) >> 1;        // ceil((tt/2+1)/2)
    if (rem < nc) break;
    rem -= nc; ++tt;
  }
  const int ntile = (tt >> 1) + 1;
  const int sb = rem * 2;
  const int se = (sb + 2 < ntile) ? sb + 2 : ntile;
  const int t0 = tt * 32;

  const float gp = log1pf(expf(gamma[h]));
  const float nrp = -log1pf(expf(rho[h]));      // -rho softplus (pow exponent)
  const size_t base8 = ((size_t)b * TSEQ) * DMODEL + h * 64;

  __shared__ unsigned qs8[16][36];   // [kk4][t]
  __shared__ unsigned ks8[16][68];   // [kk4][s]
  __shared__ hf awt[32][72];         // AW [t][s] row-major (+pad)
  __shared__ hf vsm[64][72];         // V  [d][s] row-major (+pad)

  const int tid = threadIdx.x, tx = tid & 15, ty = tid >> 4;
  const int tx4 = tx * 4, ty2 = ty * 2;
  const int lane = tid & 63, wv = tid >> 6;
  const float SCALE_D = 1.0f / (127.5f * 8.0f);   // sad -> l1/Dh*sqrt(Dh)

  {  // Q tile 32x64 u8, transposed into dword-rows
    const int r = tid >> 3, p = (tid & 7) * 2;
    uint2 a = *(const uint2*)&Qb[base8 + (size_t)(t0 + r) * DMODEL + (tid & 7) * 8];
    qs8[p + 0][r] = a.x;
    qs8[p + 1][r] = a.y;
  }

  float rsum[2] = {};
  f32x4 cacc[2] = {};                // MFMA accumulators: [mtile] x 4 f32

  const int vd = tid >> 2, vs16 = (tid & 3) * 16;
  const int arow = lane & 15;        // MFMA m/n index
  const int koff = (lane >> 4) * 8;  // MFMA k sub-offset

  for (int st = sb; st < se; ++st) {
    const int s0 = st * 64;
    __syncthreads();
    {  // K tile 64x64 u8 (transposed dwords)
      const int r = tid >> 2, p = (tid & 3) * 4;
      uint4 a = *(const uint4*)&Kb[base8 + (size_t)(s0 + r) * DMODEL + (tid & 3) * 16];
      ks8[p + 0][r] = a.x;
      ks8[p + 1][r] = a.y;
      ks8[p + 2][r] = a.z;
      ks8[p + 3][r] = a.w;
      // V tile: transposed f16 in HBM -> plain [d][s] rows in LDS
      const hf* vsrc = &Vt[((size_t)bh * 64 + vd) * 1024 + s0 + vs16];
      *(h8*)&vsm[vd][vs16 + 0] = *(const h8*)vsrc;
      *(h8*)&vsm[vd][vs16 + 8] = *(const h8*)(vsrc + 8);
    }
    __syncthreads();

    // L1 via v_sad_u8 (exact integer)
    unsigned sacc[2][4] = {};
#pragma unroll
    for (int kk = 0; kk < 16; kk++) {
      uint2 qa = *(const uint2*)&qs8[kk][ty2];
      uint4 kb4 = *(const uint4*)&ks8[kk][tx4];
      const unsigned kk4[4] = {kb4.x, kb4.y, kb4.z, kb4.w};
#pragma unroll
      for (int j = 0; j < 4; j++) {
        sacc[0][j] = sad8(qa.x, kk4[j], sacc[0][j]);
        sacc[1][j] = sad8(qa.y, kk4[j], sacc[1][j]);
      }
    }

    // kernel weights + causal mask -> f16 [t][s] in LDS
#pragma unroll
    for (int i = 0; i < 2; i++) {
      const int tg = t0 + ty2 + i;
      h4 pk;
#pragma unroll
      for (int j = 0; j < 4; j++) {
        const int sg = s0 + tx4 + j;
        const float dist = (float)sacc[i][j] * SCALE_D;
        const float bsx = fmaf(gp, dist * dist, 1.0f + 1e-6f);
        float aw = fpow_ge1(bsx, nrp);              // bsx>=1: raw log/exp
        aw = (sg <= tg) ? aw : 0.0f;
        pk[j] = (hf)aw;
        rsum[i] += aw;
      }
      *(h4*)&awt[ty2 + i][tx4] = pk;
    }
    __syncthreads();

    // PV: O[32x64] += AW[32x64] @ V[64x64] via MFMA (wave wv owns d-cols 16wv..)
#ifdef HAVE_MFMA
#pragma unroll
    for (int ks = 0; ks < 2; ks++) {
      h8 bfrag = *(const h8*)&vsm[wv * 16 + arow][ks * 32 + koff];
      h8 afr0  = *(const h8*)&awt[arow]          [ks * 32 + koff];
      h8 afr1  = *(const h8*)&awt[16 + arow]     [ks * 32 + koff];
      cacc[0] = __builtin_amdgcn_mfma_f32_16x16x32_f16(afr0, bfrag, cacc[0], 0, 0, 0);
      cacc[1] = __builtin_amdgcn_mfma_f32_16x16x32_f16(afr1, bfrag, cacc[1], 0, 0, 0);
    }
#else
    {
      const int crow = (lane >> 4) * 4;
      const int d = wv * 16 + (lane & 15);
#pragma unroll
      for (int mt = 0; mt < 2; mt++)
#pragma unroll
        for (int r = 0; r < 4; r++) {
          const int t = mt * 16 + crow + r;
          float s = cacc[mt][r];
          for (int si = 0; si < 64; si++)
            s += (float)awt[t][si] * (float)vsm[d][si];
          cacc[mt][r] = s;
        }
    }
#endif
  }

#pragma unroll
  for (int off = 1; off < 16; off <<= 1) {
    rsum[0] += __shfl_xor(rsum[0], off);
    rsum[1] += __shfl_xor(rsum[1], off);
  }
  float* aO = accO + ((size_t)bh * TSEQ + t0) * 64;
  {   // C/D layout: col=lane&15 (d), row=(lane>>4)*4+reg (t)
    const int crow = (lane >> 4) * 4;
    const int ccol = wv * 16 + (lane & 15);
#pragma unroll
    for (int mt = 0; mt < 2; mt++)
#pragma unroll
      for (int r = 0; r < 4; r++)
        atomicAdd(&aO[(size_t)(mt * 16 + crow + r) * 64 + ccol], cacc[mt][r]);
  }
#pragma unroll
  for (int i = 0; i < 2; i++)
    if (tx == 0) atomicAdd(&accR[bh * TSEQ + t0 + ty2 + i], rsum[i]);
}

// ---------------- wo GEMM + residual, attn-normalize fused in staging ------
// Xn = accO [bh][1024][64]; logical attn[n][c] = Xn[bh(n,c)][t(n)][c&63]/rsum.
__global__ __launch_bounds__(256) void gemm_res_kernel(
    const float* __restrict__ Xn, const float* __restrict__ accR,
    const float* __restrict__ W,
    const float* __restrict__ bias, const float* __restrict__ Res,
    float* __restrict__ Out)
{
  const int m0 = blockIdx.x * 64, n0 = blockIdx.y * 64;
  __shared__ float xs[16][68];
  __shared__ float wsm[16][68];
  const int tid = threadIdx.x, tx = tid & 15, ty = tid >> 4;
  const int lr = tid >> 2, lc4 = (tid & 3) * 4;
  float acc[4][4] = {};
  const int n = n0 + lr;
  const float* wp = &W[(size_t)(m0 + lr) * DMODEL + lc4];
  for (int k0 = 0; k0 < DMODEL; k0 += 16) {
    const int c = k0 + lc4;
    const size_t arow = ((size_t)((n >> 10) * 8 + (c >> 6))) * TSEQ + (n & 1023);
    float4 xv = *(const float4*)&Xn[arow * 64 + (c & 63)];
    const float inv = 1.0f / (accR[arow] + 1e-6f);
    xv.x *= inv; xv.y *= inv; xv.z *= inv; xv.w *= inv;
    float4 wv = *(const float4*)(wp + k0);
    __syncthreads();
    xs [lc4 + 0][lr] = xv.x; xs [lc4 + 1][lr] = xv.y; xs [lc4 + 2][lr] = xv.z; xs [lc4 + 3][lr] = xv.w;
    wsm[lc4 + 0][lr] = wv.x; wsm[lc4 + 1][lr] = wv.y; wsm[lc4 + 2][lr] = wv.z; wsm[lc4 + 3][lr] = wv.w;
    __syncthreads();
#pragma unroll
    for (int kk = 0; kk < 16; kk++) {
      float4 av = *(const float4*)&xs[kk][ty * 4];
      float4 bv = *(const float4*)&wsm[kk][tx * 4];
      const float aa[4] = {av.x, av.y, av.z, av.w};
      const float bs[4] = {bv.x, bv.y, bv.z, bv.w};
#pragma unroll
      for (int i = 0; i < 4; i++)
#pragma unroll
        for (int j = 0; j < 4; j++) acc[i][j] = fmaf(aa[i], bs[j], acc[i][j]);
    }
  }
#pragma unroll
  for (int i = 0; i < 4; i++) {
    const int nn = n0 + ty * 4 + i;
    float o[4];
#pragma unroll
    for (int j = 0; j < 4; j++) {
      const int m = m0 + tx * 4 + j;
      o[j] = acc[i][j] + bias[m] + Res[(size_t)nn * DMODEL + m];
    }
    *(float4*)&Out[(size_t)nn * DMODEL + m0 + tx * 4] = make_float4(o[0], o[1], o[2], o[3]);
  }
}

// ---------------- final combine (fused out-proxy epilogue) ------------------
// out = x2 + f + 0.5*|shift(h) - sigmoid(dir_w)|, f from u16 split-K partials
// (each partial = round(acc_z/2); sum of 4 slices, scale 2x folded into invf).
__global__ void final_kernel(const float* __restrict__ x2,
                             const unsigned short* __restrict__ pf,
                             const float* __restrict__ outg,
                             const float* __restrict__ h,
                             const float* __restrict__ dirw,
                             float* __restrict__ out)
{
  const int i4 = blockIdx.x * 256 + threadIdx.x;
  const int n = i4 >> 7;
  const int t = n & (TSEQ - 1);
  const int d4 = (i4 & 127) * 4;
  float4 xv = *(const float4*)&x2[(size_t)i4 * 4];
  const size_t off = (size_t)i4 * 4;
  unsigned s[4] = {};
#pragma unroll
  for (int z = 0; z < 4; z++) {
    uint2 a = *(const uint2*)&pf[(size_t)z * ((size_t)NROWS * DMODEL) + off];
    s[0] += (a.x & 0xffffu);
    s[1] += (a.x >> 16);
    s[2] += (a.y & 0xffffu);
    s[3] += (a.y >> 16);
  }
  float4 hv = make_float4(0.f, 0.f, 0.f, 0.f);
  if (t != 0) hv = *(const float4*)&h[(size_t)(i4 - 128) * 4];
  const float xx[4] = {xv.x, xv.y, xv.z, xv.w};
  const float hh[4] = {hv.x, hv.y, hv.z, hv.w};
  const float invf = 2.0f / (127.5f * 2048.0f);   // 2x: partials store acc/2
  float o[4];
#pragma unroll
  for (int j = 0; j < 4; j++) {
    const float f = (0.5f - (float)s[j] * invf) * outg[d4 + j];
    const float sg = 1.0f / (1.0f + __expf(-dirw[d4 + j]));
    o[j] = xx[j] + f + 0.5f * fabsf(hh[j] - sg);
  }
  *(float4*)&out[(size_t)i4 * 4] = make_float4(o[0], o[1], o[2], o[3]);
}

// ---------------------------------------------------------------------------
extern "C" void kernel_launch(void* const* d_in, const int* in_sizes, int n_in,
                              void* d_out, int out_size, void* d_ws, size_t ws_size,
                              hipStream_t stream)
{
  (void)in_sizes; (void)n_in; (void)out_size;
  const float* x      = (const float*)d_in[0];
  const float* ln1_w  = (const float*)d_in[1];
  const float* ln1_b  = (const float*)d_in[2];
  const float* wq_w   = (const float*)d_in[3];
  const float* wq_g   = (const float*)d_in[4];
  const float* wk_w   = (const float*)d_in[5];
  const float* wk_g   = (const float*)d_in[6];
  const float* wv_w   = (const float*)d_in[7];
  const float* wv_g   = (const float*)d_in[8];
  const float* wo_w   = (const float*)d_in[9];
  const float* wo_b   = (const float*)d_in[10];
  const float* gamma  = (const float*)d_in[11];
  const float* rho    = (const float*)d_in[12];
  const float* ln2_w  = (const float*)d_in[13];
  const float* ln2_b  = (const float*)d_in[14];
  const float* gate_w = (const float*)d_in[15];
  const float* gate_g = (const float*)d_in[16];
  const float* val_w  = (const float*)d_in[17];
  const float* val_g  = (const float*)d_in[18];
  const float* out_w  = (const float*)d_in[19];
  const float* out_g  = (const float*)d_in[20];
  const float* dir_w  = (const float*)d_in[21];
  float* out = (float*)d_out;

  if (ws_size < ((size_t)32 << 20)) return;
  unsigned char* wsb = (unsigned char*)d_ws;

  unsigned char* w8   = wsb;                          // [0,2MB) weights u8
  unsigned char* x8   = wsb + ((size_t)2 << 20);      // xt8; later ht8
  unsigned char* q8b  = wsb + ((size_t)3 << 20);
  unsigned char* k8b  = wsb + ((size_t)4 << 20);
  hf*            vt16 = (hf*)(wsb + ((size_t)5 << 20));       // 2MB (dead post-4)
  unsigned char* w9   = wsb + ((size_t)5 << 20);      // out_w u8 (reuses vt16)
  unsigned char* gvt8 = wsb + ((size_t)7 << 20);              // 4MB
  float*         accO = (float*)(wsb + ((size_t)11 << 20));   // 4MB
  float*         accR = (float*)(wsb + ((size_t)15 << 20));   // 64KB (contig w/ accO)
  unsigned short* pf  = (unsigned short*)(wsb + ((size_t)16 << 20)); // 8MB, 4 u16 slices
  float*         x2   = (float*)(wsb + ((size_t)24 << 20));   // 4MB
  float*         hbuf = (float*)(wsb + ((size_t)28 << 20));   // 4MB

  // 1+2. xt8 = q8(tanh(LN1(x))) [+ zero accO/accR] and q/k/v weights -> u8
  fused1_kernel<<<NROWS + 768, 256, 0, stream>>>(
      x, ln1_w, ln1_b, x8, (float4*)accO, wq_w, wk_w, wv_w, w8);

  // 3. q,k,v cdists (SAD), z-split; q/k -> u8, v -> f16 transposed
  {
    CP cp; cp.g0 = wq_g; cp.g1 = wk_g; cp.g2 = wv_g;
    cdistq_kernel<1, 1><<<dim3(16, 32, 3), 256, 0, stream>>>(
        x8, w8, cp, q8b, k8b, vt16, nullptr, nullptr,
        512, 512, 512, 1.0f / (127.5f * 512.0f));
  }

  // 4. attention: split-S partial (accO/accR pre-zeroed by step 1)
  attn_part_kernel<<<dim3(144, 16), 256, 0, stream>>>(q8b, k8b, vt16,
                                                      gamma, rho, accO, accR);

  // 5. x2 = x + normalize(accO/accR) @ wo^T + wo_b  (normalize fused)
  gemm_res_kernel<<<dim3(8, 32), 256, 0, stream>>>(accO, accR, wo_w, wo_b, x, x2);

  // 6+7+9. h/ht8 = LN2(x2); gate/val weights -> w8; out_w -> w9 (K=2048)
  fused6_kernel<<<NROWS + 2048 + 256, 256, 0, stream>>>(
      x2, ln2_w, ln2_b, hbuf, x8, gate_w, val_w, w8, out_w, w9);

  // 8. gvt8 = q8(tanh(silu(gate)*val)), BK=64: 2048 blocks, 8/CU
  {
    CP cp; cp.g0 = gate_g; cp.g1 = val_g; cp.g2 = nullptr;
    cdistq_kernel<2, 2><<<dim3(64, 32, 1), 256, 0, stream>>>(
        x8, w8, cp, nullptr, nullptr, nullptr, gvt8, nullptr,
        2048, 512, 512, 1.0f / (127.5f * 512.0f));
  }

  // 10. out-proxy partial sums (K=2048): BK=64, split-K=4, u16 plain stores
  //     (no memset, no atomics). 2048 blocks -> 8/CU. Weights from w9.
  {
    CP cp; cp.g0 = out_g; cp.g1 = nullptr; cp.g2 = nullptr;
    cdistq_kernel<1, 3><<<dim3(16, 32, 4), 256, 0, stream>>>(
        gvt8, w9, cp, nullptr, nullptr, nullptr, nullptr, pf,
        512, 2048, 512, 0.0f);
  }

  // 11. out = x2 + f(partials) + 0.5*|shift(h) - sigmoid(dir_w)|  (fepi fused)
  final_kernel<<<1024, 256, 0, stream>>>(x2, pf, out_g, hbuf, dir_w, out);
}

// Round 10
// 132.623 us; speedup vs baseline: 2.9604x; 1.1373x over previous
//
#include <hip/hip_runtime.h>
#include <math.h>

// DeltaBlock forward, MI355X. All proxy layers / attention distances are L1-cdists
// (stop_gradient(l1-l2)+l2 == l1 forward). R7: u8 v_sad_u8 cdists (exact).
// R8: attention PV via mfma_f32_16x16x32_f16. R9/R10: occupancy + fusion.
// R11: transcendental diet. R12: u16 split-K partials. R13-R19: tile/staging
// sweep — cdist is dual-pipe saturated: VALU floor ~29us (SAD half-rate,
// measured) + LDS pipe ~26us; read/SAD ratio at VGPR-constrained optimum
// (R=C*NCD=4). R20: BK=64 + dispatch merges 11->8 (150.8us).
// R21: gemm_res (step 5) moved off the scalar-FMA VALU path onto the matrix
// pipe (f16 MFMA 16x16x32, same intrinsic as attn PV; f16 rounding ~2e-4,
// negligible vs q8's 0.03). s_setprio(1) wrapped around MFMA/SAD clusters.

#define NROWS  2048
#define DMODEL 512
#define TSEQ   1024
#define HIDDEN 2048

typedef _Float16 hf;
typedef hf h2 __attribute__((ext_vector_type(2)));
typedef hf h4 __attribute__((ext_vector_type(4)));
typedef hf h8 __attribute__((ext_vector_type(8)));
typedef float f32x4 __attribute__((ext_vector_type(4)));

#if defined(__has_builtin)
#if __has_builtin(__builtin_amdgcn_sad_u8)
#define HAVE_SAD 1
#endif
#if __has_builtin(__builtin_amdgcn_mfma_f32_16x16x32_f16)
#define HAVE_MFMA 1
#endif
#endif

__device__ __forceinline__ unsigned sad8(unsigned a, unsigned b, unsigned c) {
#ifdef HAVE_SAD
  return __builtin_amdgcn_sad_u8(a, b, c);
#else
  unsigned r;
  asm("v_sad_u8 %0, %1, %2, %3" : "=v"(r) : "v"(a), "v"(b), "v"(c));
  return r;
#endif
}

// fast tanh: sign(x)*(1-t)/(1+t), t=e^(-2|x|); err ~1e-7 << q8 step 4e-3
__device__ __forceinline__ float ftanh(float x) {
  const float t = __expf(-2.0f * fabsf(x));
  const float r = (1.0f - t) / (1.0f + t);
  return copysignf(r, x);
}

// x^p for x>=1 (no edge cases): exp2(p*log2(x)) via raw v_log/v_exp
__device__ __forceinline__ float fpow_ge1(float x, float p) {
  float lg, r;
  asm("v_log_f32 %0, %1" : "=v"(lg) : "v"(x));
  const float e = lg * p;
  asm("v_exp_f32 %0, %1" : "=v"(r) : "v"(e));
  return r;
}

__device__ __forceinline__ unsigned q8(float x) {   // tanh-range (-1,1) -> u8
  return (unsigned)(int)((x + 1.0f) * 127.5f + 0.5f);
}

struct CP { const float* g0; const float* g1; const float* g2; };

// ---------------- device bodies for fused dispatches -----------------------
// LayerNorm row n: f32 row -> (optional f32 out) + tanh-u8 out; optional
// zero-fill of accO/accR (130 float4 per block, exact).
__device__ __forceinline__ void ln_body(
    int n, const float* __restrict__ X, const float* __restrict__ w,
    const float* __restrict__ bb, float* __restrict__ outPlain,
    unsigned char* __restrict__ out8, float4* __restrict__ zf)
{
  const int tid = threadIdx.x;
  if (zf && tid < 130)
    zf[(size_t)n * 130 + tid] = make_float4(0.f, 0.f, 0.f, 0.f);
  const float* row = X + (size_t)n * DMODEL;
  float2 v = *(const float2*)&row[tid * 2];
  float s1 = v.x + v.y;
  float s2 = v.x * v.x + v.y * v.y;
#pragma unroll
  for (int off = 1; off < 64; off <<= 1) {
    s1 += __shfl_xor(s1, off);
    s2 += __shfl_xor(s2, off);
  }
  __shared__ float red[8];
  if ((tid & 63) == 0) { red[(tid >> 6) * 2] = s1; red[(tid >> 6) * 2 + 1] = s2; }
  __syncthreads();
  s1 = red[0] + red[2] + red[4] + red[6];
  s2 = red[1] + red[3] + red[5] + red[7];
  const float mu   = s1 * (1.0f / DMODEL);
  const float var  = s2 * (1.0f / DMODEL) - mu * mu;
  const float rstd = rsqrtf(var + 1e-5f);
  const int d = tid * 2;
  const float y0 = (v.x - mu) * rstd * w[d]     + bb[d];
  const float y1 = (v.y - mu) * rstd * w[d + 1] + bb[d + 1];
  if (outPlain) *(float2*)&outPlain[(size_t)n * DMODEL + d] = make_float2(y0, y1);
  const unsigned a = q8(ftanh(y0)), b = q8(ftanh(y1));
  *(unsigned short*)&out8[(size_t)n * DMODEL + d] = (unsigned short)(a | (b << 8));
}

// tanh+q8 of one f32 row (128 threads of the half-block given by tid>>7)
__device__ __forceinline__ void cvt_body(
    const float* __restrict__ src, unsigned char* __restrict__ dst, int K)
{
  const int t = threadIdx.x & 127;
  for (int k = t * 4; k < K; k += 512) {
    float4 v = *(const float4*)&src[k];
    unsigned pk = q8(ftanh(v.x)) | (q8(ftanh(v.y)) << 8) |
                  (q8(ftanh(v.z)) << 16) | (q8(ftanh(v.w)) << 24);
    *(unsigned*)&dst[k] = pk;
  }
}

// ---------------- fused step 1+2: LN1 + q/k/v weight cvt -------------------
// grid 2048 + 768: b<2048 -> ln row b (zeroes accO/accR); else qkv-weight cvt.
__global__ __launch_bounds__(256) void fused1_kernel(
    const float* __restrict__ X, const float* __restrict__ lw,
    const float* __restrict__ lb, unsigned char* __restrict__ x8,
    float4* __restrict__ zf,
    const float* __restrict__ wq, const float* __restrict__ wk,
    const float* __restrict__ wv, unsigned char* __restrict__ w8)
{
  const int b = blockIdx.x;
  if (b < NROWS) { ln_body(b, X, lw, lb, nullptr, x8, zf); return; }
  const int c = b - NROWS;                       // [0, 768)
  const int z = c >> 8, rb = c & 255;
  const float* sb = (z == 0) ? wq : (z == 1) ? wk : wv;
  const int row = rb * 2 + (threadIdx.x >> 7);   // 512 rows per z
  cvt_body(sb + (size_t)row * 512, w8 + ((size_t)z * 512 + row) * 512, 512);
}

// ---------------- fused step 6+7+9: LN2 + gate/val cvt + out_w cvt ---------
// grid 2048 + 2048 + 256. out_w u8 goes to w9 (separate region, no w8 alias).
__global__ __launch_bounds__(256) void fused6_kernel(
    const float* __restrict__ x2, const float* __restrict__ lw,
    const float* __restrict__ lb, float* __restrict__ hbuf,
    unsigned char* __restrict__ x8,
    const float* __restrict__ gate_w, const float* __restrict__ val_w,
    unsigned char* __restrict__ w8,
    const float* __restrict__ out_w, unsigned char* __restrict__ w9)
{
  const int b = blockIdx.x;
  if (b < NROWS) { ln_body(b, x2, lw, lb, hbuf, x8, nullptr); return; }
  int c = b - NROWS;
  if (c < 2048) {                                // gate/val: 2048 rows per z
    const int z = c >> 10, rb = c & 1023;
    const float* sb = z ? val_w : gate_w;
    const int row = rb * 2 + (threadIdx.x >> 7);
    cvt_body(sb + (size_t)row * 512, w8 + ((size_t)z * 2048 + row) * 512, 512);
  } else {                                       // out_w: 512 rows, K=2048
    c -= 2048;                                   // [0, 256)
    const int row = c * 2 + (threadIdx.x >> 7);
    cvt_body(out_w + (size_t)row * 2048, w9 + (size_t)row * 2048, 2048);
  }
}

// ---------------- u8 SAD cdist kernel, kk-paired W, BK=64 ------------------
// block tile 64 rows x 32 cols, BK=64 (two 32B slabs per barrier), 256
// threads, 8 blocks/CU. X in LDS [kk][row] (b128 broadcast reads). W in LDS
// kk-PAIRED [kkp][c*68 + col*2 + (kk&1)] — one ds_write_b64 stages 2 kks;
// one b128 read serves 2 kks x 2 cols. Double-buffered, ONE barrier per 64B
// of K. s_setprio(1) during the SAD cluster (R21).
// EPI 1: QKV, blockIdx.z = {0:q, 1:k, 2:v}; q,k -> tanh u8, v -> f16 transposed.
// EPI 2: gate/val (NCD=2) -> tanh(silu(g)*v) u8.
// EPI 3: split-K partial (blockIdx.z = K-slice) -> u16 plain stores into
//        contiguous pf (slice stride NROWS*M u16); (acc+1)>>1 fits u16 at
//        Kc=512 (max 130560/2); rounding err <= 2 counts total.
template <int NCD, int EPI>
__global__ __launch_bounds__(256, 8) void cdistq_kernel(
    const unsigned char* __restrict__ X8, const unsigned char* __restrict__ W8,
    CP cp,
    unsigned char* __restrict__ o8a, unsigned char* __restrict__ o8b,
    hf* __restrict__ vt16, unsigned char* __restrict__ gvt8,
    unsigned short* __restrict__ pf,
    int M, int K, int Kc, float invK127)
{
  const int m0 = blockIdx.x * 32, n0 = blockIdx.y * 64;
  const int zc = (EPI == 1) ? blockIdx.z : 0;          // QKV: z picks cdist
  const int kb = (EPI == 3) ? blockIdx.z * Kc : 0;     // split-K slice
  constexpr int WROW = NCD * 68 + 4;
  __shared__ __align__(16) unsigned xs[2][16][68];     // [dbuf][kk][row]
  __shared__ __align__(16) unsigned ws[2][8][WROW];    // [dbuf][kkp][c*68+col*2+half]
  const int tid = threadIdx.x, tx = tid & 15, ty = tid >> 4;
  unsigned acc[NCD][4][2] = {};

  // X staging: row rs, kk dwords ps..ps+1 (per slab)
  const int rs = tid >> 2, ps = (tid & 3) * 2;
  // W staging: 128 threads per c; col wcol, kkp = (half&3) (per slab)
  const int half = tid & 127;
  const int wc = (NCD == 2) ? (tid >> 7) : 0;
  const int wcol = half >> 2, kkw = half & 3;

  const unsigned char* xp = X8 + (size_t)(n0 + rs) * K + kb + (tid & 3) * 8;
  const unsigned char* wq = W8 + (size_t)(zc + wc) * M * K +
                            (size_t)(m0 + wcol) * K + kb + kkw * 8;

  uint2 xv0 = *(const uint2*)xp;
  uint2 xv1 = *(const uint2*)(xp + 32);
  uint2 wv0 = *(const uint2*)wq;
  uint2 wv1 = *(const uint2*)(wq + 32);

  int p = 0;
#pragma unroll 1
  for (int k0 = 0; k0 < Kc; k0 += 64) {
    // stage both slabs from regs (one barrier per 64B; dbuf keeps next-iter
    // writes off the buffer still being read)
    xs[p][ps + 0][rs] = xv0.x;
    xs[p][ps + 1][rs] = xv0.y;
    xs[p][8 + ps + 0][rs] = xv1.x;
    xs[p][8 + ps + 1][rs] = xv1.y;
    *(uint2*)&ws[p][kkw][wc * 68 + wcol * 2]     = make_uint2(wv0.x, wv0.y);
    *(uint2*)&ws[p][4 + kkw][wc * 68 + wcol * 2] = make_uint2(wv1.x, wv1.y);
    // prefetch next k-slabs into regs (dummy re-read of 0 on last iter)
    const int kn = (k0 + 64 < Kc) ? k0 + 64 : 0;
    xv0 = *(const uint2*)(xp + kn);
    xv1 = *(const uint2*)(xp + kn + 32);
    wv0 = *(const uint2*)(wq + kn);
    wv1 = *(const uint2*)(wq + kn + 32);
    __syncthreads();

    __builtin_amdgcn_s_setprio(1);
#pragma unroll
    for (int kkp = 0; kkp < 8; kkp++) {
      uint4 a0 = *(const uint4*)&xs[p][kkp * 2 + 0][ty * 4];
      uint4 a1 = *(const uint4*)&xs[p][kkp * 2 + 1][ty * 4];
      const unsigned ae[4] = {a0.x, a0.y, a0.z, a0.w};
      const unsigned ao[4] = {a1.x, a1.y, a1.z, a1.w};
#pragma unroll
      for (int c = 0; c < NCD; c++) {
        // b4 = {col0@kk_even, col0@kk_odd, col1@kk_even, col1@kk_odd}
        uint4 b4 = *(const uint4*)&ws[p][kkp][c * 68 + tx * 4];
#pragma unroll
        for (int i = 0; i < 4; i++) {
          acc[c][i][0] = sad8(ae[i], b4.x, acc[c][i][0]);
          acc[c][i][0] = sad8(ao[i], b4.y, acc[c][i][0]);
          acc[c][i][1] = sad8(ae[i], b4.z, acc[c][i][1]);
          acc[c][i][1] = sad8(ao[i], b4.w, acc[c][i][1]);
        }
      }
    }
    __builtin_amdgcn_s_setprio(0);
    p ^= 1;
  }

  if constexpr (EPI == 1) {                  // QKV, z-selected cdist (NCD=1)
    if (zc < 2) {                            // q or k -> tanh u8
      unsigned char* o8 = zc ? o8b : o8a;
      const float* gn = zc ? cp.g1 : cp.g0;
#pragma unroll
      for (int i = 0; i < 4; i++) {
        const int n = n0 + ty * 4 + i;
        unsigned pk = 0;
#pragma unroll
        for (int j = 0; j < 2; j++) {
          const int m = m0 + tx * 2 + j;
          const float val = (0.5f - (float)acc[0][i][j] * invK127) * gn[m];
          pk |= q8(ftanh(val)) << (8 * j);
        }
        *(unsigned short*)&o8[(size_t)n * M + m0 + tx * 2] = (unsigned short)pk;
      }
    } else {                                 // v -> f16 transposed [bh][d][t]
#pragma unroll
      for (int i = 0; i < 4; i++) {
        const int n = n0 + ty * 4 + i;
        const int b = n >> 10, t = n & 1023;
#pragma unroll
        for (int j = 0; j < 2; j++) {
          const int m = m0 + tx * 2 + j;
          const float vv = (0.5f - (float)acc[0][i][j] * invK127) * cp.g2[m];
          vt16[((size_t)(b * 8 + (m >> 6)) * 64 + (m & 63)) * 1024 + t] = (hf)vv;
        }
      }
    }
  } else if constexpr (EPI == 2) {           // gate/val: NCD=2
#pragma unroll
    for (int i = 0; i < 4; i++) {
      const int n = n0 + ty * 4 + i;
      unsigned pk = 0;
#pragma unroll
      for (int j = 0; j < 2; j++) {
        const int m = m0 + tx * 2 + j;
        float g = (0.5f - (float)acc[0][i][j] * invK127) * cp.g0[m];
        g = g / (1.0f + __expf(-g));         // silu
        const float vv = (0.5f - (float)acc[1][i][j] * invK127) * cp.g1[m];
        pk |= q8(ftanh(g * vv)) << (8 * j);
      }
      *(unsigned short*)&gvt8[(size_t)n * M + m0 + tx * 2] = (unsigned short)pk;
    }
  } else {                                   // EPI==3: u16 partials, plain stores
    unsigned short* pz = pf + (size_t)blockIdx.z * ((size_t)NROWS * M);
#pragma unroll
    for (int i = 0; i < 4; i++) {
      const int n = n0 + ty * 4 + i;
      const unsigned p0 = (acc[0][i][0] + 1) >> 1;
      const unsigned p1 = (acc[0][i][1] + 1) >> 1;
      *(unsigned*)&pz[(size_t)n * M + m0 + tx * 2] = p0 | (p1 << 16);
    }
  }
}

// ---------------- attention: split-S partial (u8 SAD QK, MFMA PV) ----------
// grid (144, 16): chunk = (tt, <=2 s-tiles). Per bh: sum ceil((tt/2+1)/2) = 144.
__global__ __launch_bounds__(256) void attn_part_kernel(
    const unsigned char* __restrict__ Qb, const unsigned char* __restrict__ Kb,
    const hf* __restrict__ Vt,
    const float* __restrict__ gamma, const float* __restrict__ rho,
    float* __restrict__ accO, float* __restrict__ accR)
{
  const int bh = blockIdx.y, b = bh >> 3, h = bh & 7;
  int rem = 143 - (int)blockIdx.x;              // heavy (high-tt) chunks first
  int tt = 0;
  for (;;) {
    const int nc = ((tt >> 1) + 2) >> 1;        // ceil((tt/2+1)/2)
    if (rem < nc) break;
    rem -= nc; ++tt;
  }
  const int ntile = (tt >> 1) + 1;
  const int sb = rem * 2;
  const int se = (sb + 2 < ntile) ? sb + 2 : ntile;
  const int t0 = tt * 32;

  const float gp = log1pf(expf(gamma[h]));
  const float nrp = -log1pf(expf(rho[h]));      // -rho softplus (pow exponent)
  const size_t base8 = ((size_t)b * TSEQ) * DMODEL + h * 64;

  __shared__ unsigned qs8[16][36];   // [kk4][t]
  __shared__ unsigned ks8[16][68];   // [kk4][s]
  __shared__ hf awt[32][72];         // AW [t][s] row-major (+pad)
  __shared__ hf vsm[64][72];         // V  [d][s] row-major (+pad)

  const int tid = threadIdx.x, tx = tid & 15, ty = tid >> 4;
  const int tx4 = tx * 4, ty2 = ty * 2;
  const int lane = tid & 63, wv = tid >> 6;
  const float SCALE_D = 1.0f / (127.5f * 8.0f);   // sad -> l1/Dh*sqrt(Dh)

  {  // Q tile 32x64 u8, transposed into dword-rows
    const int r = tid >> 3, p = (tid & 7) * 2;
    uint2 a = *(const uint2*)&Qb[base8 + (size_t)(t0 + r) * DMODEL + (tid & 7) * 8];
    qs8[p + 0][r] = a.x;
    qs8[p + 1][r] = a.y;
  }

  float rsum[2] = {};
  f32x4 cacc[2] = {};                // MFMA accumulators: [mtile] x 4 f32

  const int vd = tid >> 2, vs16 = (tid & 3) * 16;
  const int arow = lane & 15;        // MFMA m/n index
  const int koff = (lane >> 4) * 8;  // MFMA k sub-offset

  for (int st = sb; st < se; ++st) {
    const int s0 = st * 64;
    __syncthreads();
    {  // K tile 64x64 u8 (transposed dwords)
      const int r = tid >> 2, p = (tid & 3) * 4;
      uint4 a = *(const uint4*)&Kb[base8 + (size_t)(s0 + r) * DMODEL + (tid & 3) * 16];
      ks8[p + 0][r] = a.x;
      ks8[p + 1][r] = a.y;
      ks8[p + 2][r] = a.z;
      ks8[p + 3][r] = a.w;
      // V tile: transposed f16 in HBM -> plain [d][s] rows in LDS
      const hf* vsrc = &Vt[((size_t)bh * 64 + vd) * 1024 + s0 + vs16];
      *(h8*)&vsm[vd][vs16 + 0] = *(const h8*)vsrc;
      *(h8*)&vsm[vd][vs16 + 8] = *(const h8*)(vsrc + 8);
    }
    __syncthreads();

    // L1 via v_sad_u8 (exact integer)
    unsigned sacc[2][4] = {};
#pragma unroll
    for (int kk = 0; kk < 16; kk++) {
      uint2 qa = *(const uint2*)&qs8[kk][ty2];
      uint4 kb4 = *(const uint4*)&ks8[kk][tx4];
      const unsigned kk4[4] = {kb4.x, kb4.y, kb4.z, kb4.w};
#pragma unroll
      for (int j = 0; j < 4; j++) {
        sacc[0][j] = sad8(qa.x, kk4[j], sacc[0][j]);
        sacc[1][j] = sad8(qa.y, kk4[j], sacc[1][j]);
      }
    }

    // kernel weights + causal mask -> f16 [t][s] in LDS
#pragma unroll
    for (int i = 0; i < 2; i++) {
      const int tg = t0 + ty2 + i;
      h4 pk;
#pragma unroll
      for (int j = 0; j < 4; j++) {
        const int sg = s0 + tx4 + j;
        const float dist = (float)sacc[i][j] * SCALE_D;
        const float bsx = fmaf(gp, dist * dist, 1.0f + 1e-6f);
        float aw = fpow_ge1(bsx, nrp);              // bsx>=1: raw log/exp
        aw = (sg <= tg) ? aw : 0.0f;
        pk[j] = (hf)aw;
        rsum[i] += aw;
      }
      *(h4*)&awt[ty2 + i][tx4] = pk;
    }
    __syncthreads();

    // PV: O[32x64] += AW[32x64] @ V[64x64] via MFMA (wave wv owns d-cols 16wv..)
#ifdef HAVE_MFMA
    __builtin_amdgcn_s_setprio(1);
#pragma unroll
    for (int ks = 0; ks < 2; ks++) {
      h8 bfrag = *(const h8*)&vsm[wv * 16 + arow][ks * 32 + koff];
      h8 afr0  = *(const h8*)&awt[arow]          [ks * 32 + koff];
      h8 afr1  = *(const h8*)&awt[16 + arow]     [ks * 32 + koff];
      cacc[0] = __builtin_amdgcn_mfma_f32_16x16x32_f16(afr0, bfrag, cacc[0], 0, 0, 0);
      cacc[1] = __builtin_amdgcn_mfma_f32_16x16x32_f16(afr1, bfrag, cacc[1], 0, 0, 0);
    }
    __builtin_amdgcn_s_setprio(0);
#else
    {
      const int crow = (lane >> 4) * 4;
      const int d = wv * 16 + (lane & 15);
#pragma unroll
      for (int mt = 0; mt < 2; mt++)
#pragma unroll
        for (int r = 0; r < 4; r++) {
          const int t = mt * 16 + crow + r;
          float s = cacc[mt][r];
          for (int si = 0; si < 64; si++)
            s += (float)awt[t][si] * (float)vsm[d][si];
          cacc[mt][r] = s;
        }
    }
#endif
  }

#pragma unroll
  for (int off = 1; off < 16; off <<= 1) {
    rsum[0] += __shfl_xor(rsum[0], off);
    rsum[1] += __shfl_xor(rsum[1], off);
  }
  float* aO = accO + ((size_t)bh * TSEQ + t0) * 64;
  {   // C/D layout: col=lane&15 (d), row=(lane>>4)*4+reg (t)
    const int crow = (lane >> 4) * 4;
    const int ccol = wv * 16 + (lane & 15);
#pragma unroll
    for (int mt = 0; mt < 2; mt++)
#pragma unroll
      for (int r = 0; r < 4; r++)
        atomicAdd(&aO[(size_t)(mt * 16 + crow + r) * 64 + ccol], cacc[mt][r]);
  }
#pragma unroll
  for (int i = 0; i < 2; i++)
    if (tx == 0) atomicAdd(&accR[bh * TSEQ + t0 + ty2 + i], rsum[i]);
}

// ---------------- wo GEMM + residual via f16 MFMA (R21) --------------------
// tile 32n x 64m, 256 thr, 4 waves; wave wv owns m-cols 16wv..+15.
// out[n][m] = sum_k A[n][k]*B[m][k] with A = normalized attn (f16),
// B = wo rows (f16) — both k-major, same mfma pattern as attn PV.
// f16 rounding adds ~2e-4 abs err (q8 error 0.03 dominates). Epilogue f32.
__global__ __launch_bounds__(256) void gemm_res_kernel(
    const float* __restrict__ Xn, const float* __restrict__ accR,
    const float* __restrict__ W,
    const float* __restrict__ bias, const float* __restrict__ Res,
    float* __restrict__ Out)
{
  const int m0 = blockIdx.x * 64, n0 = blockIdx.y * 32;
  __shared__ hf xnb[32][40];   // [n][k] f16 (+pad)
  __shared__ hf wb[64][40];    // [m][k] f16 (+pad)
  const int tid = threadIdx.x, lane = tid & 63, wv = tid >> 6;
  const int arow = lane & 15, koff = (lane >> 4) * 8;
  f32x4 acc0 = {}, acc1 = {};
  const int xr = tid >> 3, xk = (tid & 7) * 4;   // Xn: 8 thr/row, float4
  const int wr = tid >> 2, wk = (tid & 3) * 8;   // W: 4 thr/row, 2x float4
  const int n = n0 + xr;

  for (int k0 = 0; k0 < DMODEL; k0 += 32) {
    const int c = k0 + xk;                       // c>>6 constant within k-step
    const size_t ar = ((size_t)((n >> 10) * 8 + (c >> 6))) * TSEQ + (n & 1023);
    float4 xv = *(const float4*)&Xn[ar * 64 + (c & 63)];
    const float inv = 1.0f / (accR[ar] + 1e-6f);
    float4 w0 = *(const float4*)&W[(size_t)(m0 + wr) * DMODEL + k0 + wk];
    float4 w1 = *(const float4*)&W[(size_t)(m0 + wr) * DMODEL + k0 + wk + 4];
    __syncthreads();
    h4 xh = { (hf)(xv.x * inv), (hf)(xv.y * inv),
              (hf)(xv.z * inv), (hf)(xv.w * inv) };
    *(h4*)&xnb[xr][xk] = xh;
    h8 wh = { (hf)w0.x, (hf)w0.y, (hf)w0.z, (hf)w0.w,
              (hf)w1.x, (hf)w1.y, (hf)w1.z, (hf)w1.w };
    *(h8*)&wb[wr][wk] = wh;
    __syncthreads();
#ifdef HAVE_MFMA
    h8 bfrag = *(const h8*)&wb[wv * 16 + arow][koff];
    h8 a0 = *(const h8*)&xnb[arow][koff];
    h8 a1 = *(const h8*)&xnb[16 + arow][koff];
    acc0 = __builtin_amdgcn_mfma_f32_16x16x32_f16(a0, bfrag, acc0, 0, 0, 0);
    acc1 = __builtin_amdgcn_mfma_f32_16x16x32_f16(a1, bfrag, acc1, 0, 0, 0);
#else
    {
      const int crow = (lane >> 4) * 4;
      const int m = wv * 16 + (lane & 15);
#pragma unroll
      for (int s = 0; s < 2; s++)
#pragma unroll
        for (int r = 0; r < 4; r++) {
          float sacc = s ? acc1[r] : acc0[r];
          const int nn = s * 16 + crow + r;
          for (int kk = 0; kk < 32; kk++)
            sacc += (float)xnb[nn][kk] * (float)wb[m][kk];
          if (s) acc1[r] = sacc; else acc0[r] = sacc;
        }
    }
#endif
  }
  // C/D layout: col=lane&15 (m within wave), row=(lane>>4)*4+reg (n)
  const int crow = (lane >> 4) * 4;
  const int ccol = m0 + wv * 16 + (lane & 15);
  const float bv = bias[ccol];
#pragma unroll
  for (int s = 0; s < 2; s++)
#pragma unroll
    for (int r = 0; r < 4; r++) {
      const int nn = n0 + s * 16 + crow + r;
      const float v = s ? acc1[r] : acc0[r];
      Out[(size_t)nn * DMODEL + ccol] = v + bv + Res[(size_t)nn * DMODEL + ccol];
    }
}

// ---------------- final combine (fused out-proxy epilogue) ------------------
// out = x2 + f + 0.5*|shift(h) - sigmoid(dir_w)|, f from u16 split-K partials
// (each partial = round(acc_z/2); sum of 4 slices, scale 2x folded into invf).
__global__ void final_kernel(const float* __restrict__ x2,
                             const unsigned short* __restrict__ pf,
                             const float* __restrict__ outg,
                             const float* __restrict__ h,
                             const float* __restrict__ dirw,
                             float* __restrict__ out)
{
  const int i4 = blockIdx.x * 256 + threadIdx.x;
  const int n = i4 >> 7;
  const int t = n & (TSEQ - 1);
  const int d4 = (i4 & 127) * 4;
  float4 xv = *(const float4*)&x2[(size_t)i4 * 4];
  const size_t off = (size_t)i4 * 4;
  unsigned s[4] = {};
#pragma unroll
  for (int z = 0; z < 4; z++) {
    uint2 a = *(const uint2*)&pf[(size_t)z * ((size_t)NROWS * DMODEL) + off];
    s[0] += (a.x & 0xffffu);
    s[1] += (a.x >> 16);
    s[2] += (a.y & 0xffffu);
    s[3] += (a.y >> 16);
  }
  float4 hv = make_float4(0.f, 0.f, 0.f, 0.f);
  if (t != 0) hv = *(const float4*)&h[(size_t)(i4 - 128) * 4];
  const float xx[4] = {xv.x, xv.y, xv.z, xv.w};
  const float hh[4] = {hv.x, hv.y, hv.z, hv.w};
  const float invf = 2.0f / (127.5f * 2048.0f);   // 2x: partials store acc/2
  float o[4];
#pragma unroll
  for (int j = 0; j < 4; j++) {
    const float f = (0.5f - (float)s[j] * invf) * outg[d4 + j];
    const float sg = 1.0f / (1.0f + __expf(-dirw[d4 + j]));
    o[j] = xx[j] + f + 0.5f * fabsf(hh[j] - sg);
  }
  *(float4*)&out[(size_t)i4 * 4] = make_float4(o[0], o[1], o[2], o[3]);
}

// ---------------------------------------------------------------------------
extern "C" void kernel_launch(void* const* d_in, const int* in_sizes, int n_in,
                              void* d_out, int out_size, void* d_ws, size_t ws_size,
                              hipStream_t stream)
{
  (void)in_sizes; (void)n_in; (void)out_size;
  const float* x      = (const float*)d_in[0];
  const float* ln1_w  = (const float*)d_in[1];
  const float* ln1_b  = (const float*)d_in[2];
  const float* wq_w   = (const float*)d_in[3];
  const float* wq_g   = (const float*)d_in[4];
  const float* wk_w   = (const float*)d_in[5];
  const float* wk_g   = (const float*)d_in[6];
  const float* wv_w   = (const float*)d_in[7];
  const float* wv_g   = (const float*)d_in[8];
  const float* wo_w   = (const float*)d_in[9];
  const float* wo_b   = (const float*)d_in[10];
  const float* gamma  = (const float*)d_in[11];
  const float* rho    = (const float*)d_in[12];
  const float* ln2_w  = (const float*)d_in[13];
  const float* ln2_b  = (const float*)d_in[14];
  const float* gate_w = (const float*)d_in[15];
  const float* gate_g = (const float*)d_in[16];
  const float* val_w  = (const float*)d_in[17];
  const float* val_g  = (const float*)d_in[18];
  const float* out_w  = (const float*)d_in[19];
  const float* out_g  = (const float*)d_in[20];
  const float* dir_w  = (const float*)d_in[21];
  float* out = (float*)d_out;

  if (ws_size < ((size_t)32 << 20)) return;
  unsigned char* wsb = (unsigned char*)d_ws;

  unsigned char* w8   = wsb;                          // [0,2MB) weights u8
  unsigned char* x8   = wsb + ((size_t)2 << 20);      // xt8; later ht8
  unsigned char* q8b  = wsb + ((size_t)3 << 20);
  unsigned char* k8b  = wsb + ((size_t)4 << 20);
  hf*            vt16 = (hf*)(wsb + ((size_t)5 << 20));       // 2MB (dead post-4)
  unsigned char* w9   = wsb + ((size_t)5 << 20);      // out_w u8 (reuses vt16)
  unsigned char* gvt8 = wsb + ((size_t)7 << 20);              // 4MB
  float*         accO = (float*)(wsb + ((size_t)11 << 20));   // 4MB
  float*         accR = (float*)(wsb + ((size_t)15 << 20));   // 64KB (contig w/ accO)
  unsigned short* pf  = (unsigned short*)(wsb + ((size_t)16 << 20)); // 8MB, 4 u16 slices
  float*         x2   = (float*)(wsb + ((size_t)24 << 20));   // 4MB
  float*         hbuf = (float*)(wsb + ((size_t)28 << 20));   // 4MB

  // 1+2. xt8 = q8(tanh(LN1(x))) [+ zero accO/accR] and q/k/v weights -> u8
  fused1_kernel<<<NROWS + 768, 256, 0, stream>>>(
      x, ln1_w, ln1_b, x8, (float4*)accO, wq_w, wk_w, wv_w, w8);

  // 3. q,k,v cdists (SAD), z-split; q/k -> u8, v -> f16 transposed
  {
    CP cp; cp.g0 = wq_g; cp.g1 = wk_g; cp.g2 = wv_g;
    cdistq_kernel<1, 1><<<dim3(16, 32, 3), 256, 0, stream>>>(
        x8, w8, cp, q8b, k8b, vt16, nullptr, nullptr,
        512, 512, 512, 1.0f / (127.5f * 512.0f));
  }

  // 4. attention: split-S partial (accO/accR pre-zeroed by step 1)
  attn_part_kernel<<<dim3(144, 16), 256, 0, stream>>>(q8b, k8b, vt16,
                                                      gamma, rho, accO, accR);

  // 5. x2 = x + normalize(accO/accR) @ wo^T + wo_b  (f16 MFMA, 512 blocks)
  gemm_res_kernel<<<dim3(8, 64), 256, 0, stream>>>(accO, accR, wo_w, wo_b, x, x2);

  // 6+7+9. h/ht8 = LN2(x2); gate/val weights -> w8; out_w -> w9 (K=2048)
  fused6_kernel<<<NROWS + 2048 + 256, 256, 0, stream>>>(
      x2, ln2_w, ln2_b, hbuf, x8, gate_w, val_w, w8, out_w, w9);

  // 8. gvt8 = q8(tanh(silu(gate)*val)), BK=64: 2048 blocks, 8/CU
  {
    CP cp; cp.g0 = gate_g; cp.g1 = val_g; cp.g2 = nullptr;
    cdistq_kernel<2, 2><<<dim3(64, 32, 1), 256, 0, stream>>>(
        x8, w8, cp, nullptr, nullptr, nullptr, gvt8, nullptr,
        2048, 512, 512, 1.0f / (127.5f * 512.0f));
  }

  // 10. out-proxy partial sums (K=2048): BK=64, split-K=4, u16 plain stores
  //     (no memset, no atomics). 2048 blocks -> 8/CU. Weights from w9.
  {
    CP cp; cp.g0 = out_g; cp.g1 = nullptr; cp.g2 = nullptr;
    cdistq_kernel<1, 3><<<dim3(16, 32, 4), 256, 0, stream>>>(
        gvt8, w9, cp, nullptr, nullptr, nullptr, nullptr, pf,
        512, 2048, 512, 0.0f);
  }

  // 11. out = x2 + f(partials) + 0.5*|shift(h) - sigmoid(dir_w)|  (fepi fused)
  final_kernel<<<1024, 256, 0, stream>>>(x2, pf, out_g, hbuf, dir_w, out);
}